// Round 1
// baseline (358.497 us; speedup 1.0000x reference)
//
#include <hip/hip_runtime.h>
#include <hip/hip_bf16.h>
#include <math.h>

#define B_ 4
#define T_ 1024
#define C_ 1024
#define H_ 16
#define D_ 64
#define M_ (B_*T_)   /* 4096 rows */

typedef __bf16 bf16;
typedef __bf16 bf16x8 __attribute__((ext_vector_type(8)));
typedef float  f32x4  __attribute__((ext_vector_type(4)));

__device__ __forceinline__ void gload16(const void* g, void* l) {
  __builtin_amdgcn_global_load_lds((const __attribute__((address_space(1))) void*)g,
                                   (__attribute__((address_space(3))) void*)l,
                                   16, 0, 0);
}

// ---- weight transpose + fp32->bf16 convert: W (K x N) f32  ->  WT (N x K) bf16
__global__ __launch_bounds__(256) void wconvT(const float* __restrict__ W,
                                              bf16* __restrict__ WT, int K, int N) {
  __shared__ float tile[32][33];
  int n0 = blockIdx.x * 32, k0 = blockIdx.y * 32;
  int tx = threadIdx.x & 31, ty = threadIdx.x >> 5;  // 32 x 8
#pragma unroll
  for (int i = ty; i < 32; i += 8)
    tile[i][tx] = W[(size_t)(k0 + i) * N + n0 + tx];
  __syncthreads();
#pragma unroll
  for (int i = ty; i < 32; i += 8)
    WT[(size_t)(n0 + i) * K + k0 + tx] = (bf16)tile[tx][i];
}

// ---- LayerNorm: x (rows x 1024) f32 -> out bf16
__global__ __launch_bounds__(256) void ln_k(const float* __restrict__ x,
                                            const float* __restrict__ g,
                                            const float* __restrict__ b,
                                            bf16* __restrict__ out) {
  int row = blockIdx.x;
  int t = threadIdx.x;
  float4 xv = ((const float4*)(x + (size_t)row * C_))[t];
  float s  = xv.x + xv.y + xv.z + xv.w;
  float ss = xv.x*xv.x + xv.y*xv.y + xv.z*xv.z + xv.w*xv.w;
#pragma unroll
  for (int m = 32; m; m >>= 1) { s += __shfl_xor(s, m); ss += __shfl_xor(ss, m); }
  __shared__ float red[8];
  int wid = t >> 6;
  if ((t & 63) == 0) { red[wid] = s; red[4 + wid] = ss; }
  __syncthreads();
  s  = red[0] + red[1] + red[2] + red[3];
  ss = red[4] + red[5] + red[6] + red[7];
  float mean = s * (1.0f / C_);
  float var  = ss * (1.0f / C_) - mean * mean;
  float inv  = rsqrtf(var + 1e-5f);
  float4 gv = ((const float4*)g)[t];
  float4 bv = ((const float4*)b)[t];
  bf16* o = out + (size_t)row * C_ + t * 4;
  o[0] = (bf16)((xv.x - mean) * inv * gv.x + bv.x);
  o[1] = (bf16)((xv.y - mean) * inv * gv.y + bv.y);
  o[2] = (bf16)((xv.z - mean) * inv * gv.z + bv.z);
  o[3] = (bf16)((xv.w - mean) * inv * gv.w + bv.w);
}

// ---- GEMM: out = epi(A @ BT^T + bias [+ res])
// A: (M x K) bf16 row-major.  BT: (N x K) bf16 row-major.
// EPI: 0 = store bf16, 1 = gelu(exact erf) -> bf16, 2 = +res -> f32
template <int EPI>
__global__ __launch_bounds__(256) void gemm_k(const bf16* __restrict__ A,
                                              const bf16* __restrict__ BT,
                                              const float* __restrict__ bias,
                                              const float* __restrict__ res,
                                              void* __restrict__ outp,
                                              int N, int K) {
  __shared__ __align__(16) bf16 sA[128 * 64];
  __shared__ __align__(16) bf16 sB[128 * 64];
  int tid = threadIdx.x;
  int wid = tid >> 6, lane = tid & 63;
  int wr = wid >> 1, wc = wid & 1;            // 2x2 waves, 64x64 each
  size_t am0 = (size_t)blockIdx.x * 128;
  size_t bn0 = (size_t)blockIdx.y * 128;

  f32x4 acc[4][4];
  const f32x4 fz = {0.f, 0.f, 0.f, 0.f};
#pragma unroll
  for (int i = 0; i < 4; ++i)
#pragma unroll
    for (int j = 0; j < 4; ++j) acc[i][j] = fz;

  const int rowl = lane >> 3, sl8 = (lane & 7) * 8;
  const bf16* ag = A  + (am0 + wid * 32 + rowl) * (size_t)K + sl8;
  const bf16* bg = BT + (bn0 + wid * 32 + rowl) * (size_t)K + sl8;
  bf16* la = sA + (wid * 32) * 64;
  bf16* lb = sB + (wid * 32) * 64;

  for (int kt = 0; kt < K; kt += 64) {
#pragma unroll
    for (int i = 0; i < 4; ++i) {
      gload16(ag + kt + (size_t)(i * 8) * K, la + i * 8 * 64);
      gload16(bg + kt + (size_t)(i * 8) * K, lb + i * 8 * 64);
    }
    __syncthreads();
    bf16x8 af[2][4], bfr[2][4];
#pragma unroll
    for (int kk = 0; kk < 2; ++kk)
#pragma unroll
      for (int i = 0; i < 4; ++i) {
        af[kk][i]  = *(const bf16x8*)(sA + (wr * 64 + i * 16 + (lane & 15)) * 64 + kk * 32 + (lane >> 4) * 8);
        bfr[kk][i] = *(const bf16x8*)(sB + (wc * 64 + i * 16 + (lane & 15)) * 64 + kk * 32 + (lane >> 4) * 8);
      }
#pragma unroll
    for (int kk = 0; kk < 2; ++kk)
#pragma unroll
      for (int mi = 0; mi < 4; ++mi)
#pragma unroll
        for (int ni = 0; ni < 4; ++ni)
          acc[mi][ni] = __builtin_amdgcn_mfma_f32_16x16x32_bf16(af[kk][mi], bfr[kk][ni], acc[mi][ni], 0, 0, 0);
    __syncthreads();
  }

#pragma unroll
  for (int ni = 0; ni < 4; ++ni) {
    int col = (int)bn0 + wc * 64 + ni * 16 + (lane & 15);
    float bv = bias[col];
#pragma unroll
    for (int mi = 0; mi < 4; ++mi) {
      int row0 = (int)am0 + wr * 64 + mi * 16 + (lane >> 4) * 4;
#pragma unroll
      for (int j = 0; j < 4; ++j) {
        size_t idx = (size_t)(row0 + j) * N + col;
        float v = acc[mi][ni][j] + bv;
        if constexpr (EPI == 0) {
          ((bf16*)outp)[idx] = (bf16)v;
        } else if constexpr (EPI == 1) {
          ((bf16*)outp)[idx] = (bf16)(0.5f * v * (1.0f + erff(v * 0.70710678118f)));
        } else {
          ((float*)outp)[idx] = v + res[idx];
        }
      }
    }
  }
}

// ---- flash attention (causal). Q/K/V: (B*T, C) bf16, head h at cols h*64..h*64+63
__global__ __launch_bounds__(256) void attn_k(const bf16* __restrict__ Q,
                                              const bf16* __restrict__ Kb,
                                              const bf16* __restrict__ Vb,
                                              bf16* __restrict__ Y) {
  int bh = blockIdx.x;
  int b = bh >> 4, h = bh & 15;
  int qt = blockIdx.y;
  int q0 = qt * 64;
  int tid = threadIdx.x, wid = tid >> 6, lane = tid & 63;

  __shared__ __align__(16) bf16 sK[64 * 64];
  __shared__ __align__(16) bf16 sVT[64 * 64];
  __shared__ __align__(16) bf16 sP[4][16 * 64];

  // Q fragments (held in regs for whole kernel); wave handles 16 q-rows
  const size_t rowQ = (size_t)(b * T_ + q0 + wid * 16 + (lane & 15)) * C_ + h * 64 + (lane >> 4) * 8;
  bf16x8 qf0 = *(const bf16x8*)(Q + rowQ);
  bf16x8 qf1 = *(const bf16x8*)(Q + rowQ + 32);

  float m_run[4] = {-1e30f, -1e30f, -1e30f, -1e30f};
  float l_run[4] = {0.f, 0.f, 0.f, 0.f};
  const f32x4 fz = {0.f, 0.f, 0.f, 0.f};
  f32x4 o[4];
#pragma unroll
  for (int i = 0; i < 4; ++i) o[i] = fz;

  const bf16* kg = Kb + (size_t)(b * T_ + wid * 16 + (lane >> 3)) * C_ + h * 64 + (lane & 7) * 8;
  bf16* lk = sK + (wid * 16) * 64;

  for (int kt = 0; kt <= qt; ++kt) {
    int k0 = kt * 64;
    // stage K tile (64 x 64) via global_load_lds
#pragma unroll
    for (int i = 0; i < 2; ++i)
      gload16(kg + ((size_t)(k0 + i * 8)) * C_, lk + i * 8 * 64);
    // stage V tile transposed (reg path)
#pragma unroll
    for (int c = 0; c < 2; ++c) {
      int ch = tid + 256 * c;           // 0..511
      int r = ch >> 3, sl = ch & 7;
      bf16x8 vv = *(const bf16x8*)(Vb + (size_t)(b * T_ + k0 + r) * C_ + h * 64 + sl * 8);
#pragma unroll
      for (int j = 0; j < 8; ++j)
        sVT[(sl * 8 + j) * 64 + r] = vv[j];
    }
    __syncthreads();

    // S = Q K^T (16 x 64 per wave)
    f32x4 s[4];
#pragma unroll
    for (int ni = 0; ni < 4; ++ni) {
      bf16x8 kf0 = *(const bf16x8*)(sK + (ni * 16 + (lane & 15)) * 64 + (lane >> 4) * 8);
      bf16x8 kf1 = *(const bf16x8*)(sK + (ni * 16 + (lane & 15)) * 64 + 32 + (lane >> 4) * 8);
      f32x4 t = fz;
      t = __builtin_amdgcn_mfma_f32_16x16x32_bf16(qf0, kf0, t, 0, 0, 0);
      t = __builtin_amdgcn_mfma_f32_16x16x32_bf16(qf1, kf1, t, 0, 0, 0);
      s[ni] = t;
    }

    int rbase = q0 + wid * 16 + (lane >> 4) * 4;
    int cbase = k0 + (lane & 15);
    float tm[4] = {-1e30f, -1e30f, -1e30f, -1e30f};
#pragma unroll
    for (int ni = 0; ni < 4; ++ni)
#pragma unroll
      for (int j = 0; j < 4; ++j) {
        float v = s[ni][j] * 0.125f;
        if (cbase + ni * 16 > rbase + j) v = -1e30f;   // causal mask
        s[ni][j] = v;
        tm[j] = fmaxf(tm[j], v);
      }
#pragma unroll
    for (int j = 0; j < 4; ++j)
#pragma unroll
      for (int mk = 1; mk < 16; mk <<= 1)
        tm[j] = fmaxf(tm[j], __shfl_xor(tm[j], mk));

    float fac[4], rs[4] = {0.f, 0.f, 0.f, 0.f};
#pragma unroll
    for (int j = 0; j < 4; ++j) {
      float mn = fmaxf(m_run[j], tm[j]);
      fac[j] = __expf(m_run[j] - mn);
      m_run[j] = mn;
    }
#pragma unroll
    for (int ni = 0; ni < 4; ++ni)
#pragma unroll
      for (int j = 0; j < 4; ++j) {
        float p = __expf(s[ni][j] - m_run[j]);
        rs[j] += p;
        sP[wid][((lane >> 4) * 4 + j) * 64 + ni * 16 + (lane & 15)] = (bf16)p;
      }
#pragma unroll
    for (int j = 0; j < 4; ++j) {
#pragma unroll
      for (int mk = 1; mk < 16; mk <<= 1)
        rs[j] += __shfl_xor(rs[j], mk);
      l_run[j] = l_run[j] * fac[j] + rs[j];
    }
#pragma unroll
    for (int df = 0; df < 4; ++df)
#pragma unroll
      for (int j = 0; j < 4; ++j)
        o[df][j] *= fac[j];
    __syncthreads();   // sP visible (and sVT already staged)

    // O += P @ V
#pragma unroll
    for (int kk = 0; kk < 2; ++kk) {
      bf16x8 pf = *(const bf16x8*)(sP[wid] + (lane & 15) * 64 + kk * 32 + (lane >> 4) * 8);
#pragma unroll
      for (int df = 0; df < 4; ++df) {
        bf16x8 vf = *(const bf16x8*)(sVT + (df * 16 + (lane & 15)) * 64 + kk * 32 + (lane >> 4) * 8);
        o[df] = __builtin_amdgcn_mfma_f32_16x16x32_bf16(pf, vf, o[df], 0, 0, 0);
      }
    }
    __syncthreads();   // protect sK/sVT from next iteration's staging
  }

#pragma unroll
  for (int df = 0; df < 4; ++df)
#pragma unroll
    for (int j = 0; j < 4; ++j) {
      int row = q0 + wid * 16 + (lane >> 4) * 4 + j;
      int d = df * 16 + (lane & 15);
      Y[(size_t)(b * T_ + row) * C_ + h * 64 + d] = (bf16)(o[df][j] / l_run[j]);
    }
}

extern "C" void kernel_launch(void* const* d_in, const int* in_sizes, int n_in,
                              void* d_out, int out_size, void* d_ws, size_t ws_size,
                              hipStream_t stream) {
  (void)in_sizes; (void)n_in; (void)out_size; (void)ws_size;
  const float* x    = (const float*)d_in[0];
  const float* ln1g = (const float*)d_in[1];
  const float* ln1b = (const float*)d_in[2];
  const float* wq   = (const float*)d_in[3];
  const float* bq   = (const float*)d_in[4];
  const float* wk   = (const float*)d_in[5];
  const float* bk   = (const float*)d_in[6];
  const float* wv   = (const float*)d_in[7];
  const float* bv   = (const float*)d_in[8];
  const float* wo   = (const float*)d_in[9];
  const float* bo   = (const float*)d_in[10];
  const float* ln2g = (const float*)d_in[11];
  const float* ln2b = (const float*)d_in[12];
  const float* w1   = (const float*)d_in[13];
  const float* b1   = (const float*)d_in[14];
  const float* w2   = (const float*)d_in[15];
  const float* b2   = (const float*)d_in[16];

  char* ws = (char*)d_ws;
  const size_t MB = 1024 * 1024;
  bf16* WqT  = (bf16*)(ws +  0 * MB);   // 2 MB
  bf16* WkT  = (bf16*)(ws +  2 * MB);   // 2 MB
  bf16* WvT  = (bf16*)(ws +  4 * MB);   // 2 MB
  bf16* WoT  = (bf16*)(ws +  6 * MB);   // 2 MB
  bf16* W1T  = (bf16*)(ws +  8 * MB);   // 8 MB
  bf16* W2T  = (bf16*)(ws + 16 * MB);   // 8 MB
  bf16* hbuf = (bf16*)(ws + 24 * MB);   // 8 MB (ln1 out; reused for ln2 out)
  bf16* qb   = (bf16*)(ws + 32 * MB);   // 8 MB
  bf16* kb   = (bf16*)(ws + 40 * MB);   // 8 MB
  bf16* vb   = (bf16*)(ws + 48 * MB);   // 8 MB
  bf16* yb   = (bf16*)(ws + 56 * MB);   // 8 MB
  bf16* mb   = (bf16*)(ws + 32 * MB);   // 32 MB, reuses qb..yb (dead by then)
  float* x1  = (float*)(ws + 64 * MB);  // 16 MB     -> total 80 MB

  dim3 blk(256);
  // one-time weight convert+transpose (per call; weights are inputs)
  wconvT<<<dim3(32, 32),  blk, 0, stream>>>(wq, WqT, 1024, 1024);
  wconvT<<<dim3(32, 32),  blk, 0, stream>>>(wk, WkT, 1024, 1024);
  wconvT<<<dim3(32, 32),  blk, 0, stream>>>(wv, WvT, 1024, 1024);
  wconvT<<<dim3(32, 32),  blk, 0, stream>>>(wo, WoT, 1024, 1024);
  wconvT<<<dim3(128, 32), blk, 0, stream>>>(w1, W1T, 1024, 4096);
  wconvT<<<dim3(32, 128), blk, 0, stream>>>(w2, W2T, 4096, 1024);

  ln_k<<<M_, blk, 0, stream>>>(x, ln1g, ln1b, hbuf);
  gemm_k<0><<<dim3(32, 8),  blk, 0, stream>>>(hbuf, WqT, bq, nullptr, qb, 1024, 1024);
  gemm_k<0><<<dim3(32, 8),  blk, 0, stream>>>(hbuf, WkT, bk, nullptr, kb, 1024, 1024);
  gemm_k<0><<<dim3(32, 8),  blk, 0, stream>>>(hbuf, WvT, bv, nullptr, vb, 1024, 1024);
  attn_k<<<dim3(64, 16), blk, 0, stream>>>(qb, kb, vb, yb);
  gemm_k<2><<<dim3(32, 8),  blk, 0, stream>>>(yb, WoT, bo, x, x1, 1024, 1024);
  ln_k<<<M_, blk, 0, stream>>>(x1, ln2g, ln2b, hbuf);
  gemm_k<1><<<dim3(32, 32), blk, 0, stream>>>(hbuf, W1T, b1, nullptr, mb, 4096, 1024);
  gemm_k<2><<<dim3(32, 8),  blk, 0, stream>>>(mb, W2T, b2, x1, (float*)d_out, 1024, 4096);
}

// Round 2
// 341.367 us; speedup vs baseline: 1.0502x; 1.0502x over previous
//
#include <hip/hip_runtime.h>
#include <hip/hip_bf16.h>
#include <math.h>

#define B_ 4
#define T_ 1024
#define C_ 1024
#define H_ 16
#define D_ 64
#define M_ (B_*T_)   /* 4096 rows */

typedef __bf16 bf16;
typedef __bf16 bf16x8 __attribute__((ext_vector_type(8)));
typedef float  f32x4  __attribute__((ext_vector_type(4)));

__device__ __forceinline__ void gload16(const void* g, void* l) {
  __builtin_amdgcn_global_load_lds((const __attribute__((address_space(1))) void*)g,
                                   (__attribute__((address_space(3))) void*)l,
                                   16, 0, 0);
}

// ---- weight transpose + fp32->bf16 convert: W (K x N) f32  ->  WT (N x K) bf16
__global__ __launch_bounds__(256) void wconvT(const float* __restrict__ W,
                                              bf16* __restrict__ WT, int K, int N) {
  __shared__ float tile[32][33];
  int n0 = blockIdx.x * 32, k0 = blockIdx.y * 32;
  int tx = threadIdx.x & 31, ty = threadIdx.x >> 5;  // 32 x 8
#pragma unroll
  for (int i = ty; i < 32; i += 8)
    tile[i][tx] = W[(size_t)(k0 + i) * N + n0 + tx];
  __syncthreads();
#pragma unroll
  for (int i = ty; i < 32; i += 8)
    WT[(size_t)(n0 + i) * K + k0 + tx] = (bf16)tile[tx][i];
}

// ---- concat three 1024-f32 bias vectors
__global__ __launch_bounds__(256) void bcat(const float* __restrict__ a,
                                            const float* __restrict__ b,
                                            const float* __restrict__ c,
                                            float* __restrict__ o) {
  int i = blockIdx.x * 256 + threadIdx.x;  // 0..3071
  o[i] = (i < 1024) ? a[i] : ((i < 2048) ? b[i - 1024] : c[i - 2048]);
}

// ---- LayerNorm: x (rows x 1024) f32 -> out bf16
__global__ __launch_bounds__(256) void ln_k(const float* __restrict__ x,
                                            const float* __restrict__ g,
                                            const float* __restrict__ b,
                                            bf16* __restrict__ out) {
  int row = blockIdx.x;
  int t = threadIdx.x;
  float4 xv = ((const float4*)(x + (size_t)row * C_))[t];
  float s  = xv.x + xv.y + xv.z + xv.w;
  float ss = xv.x*xv.x + xv.y*xv.y + xv.z*xv.z + xv.w*xv.w;
#pragma unroll
  for (int m = 32; m; m >>= 1) { s += __shfl_xor(s, m); ss += __shfl_xor(ss, m); }
  __shared__ float red[8];
  int wid = t >> 6;
  if ((t & 63) == 0) { red[wid] = s; red[4 + wid] = ss; }
  __syncthreads();
  s  = red[0] + red[1] + red[2] + red[3];
  ss = red[4] + red[5] + red[6] + red[7];
  float mean = s * (1.0f / C_);
  float var  = ss * (1.0f / C_) - mean * mean;
  float inv  = rsqrtf(var + 1e-5f);
  float4 gv = ((const float4*)g)[t];
  float4 bv = ((const float4*)b)[t];
  bf16* o = out + (size_t)row * C_ + t * 4;
  o[0] = (bf16)((xv.x - mean) * inv * gv.x + bv.x);
  o[1] = (bf16)((xv.y - mean) * inv * gv.y + bv.y);
  o[2] = (bf16)((xv.z - mean) * inv * gv.z + bv.z);
  o[3] = (bf16)((xv.w - mean) * inv * gv.w + bv.w);
}

// ---- 2-phase double-buffered GEMM: out = epi(A @ BT^T + bias [+ res])
// A: (M x K) bf16 row-major.  BT: (N x K) bf16 row-major.  K % 64 == 0.
// EPI: 0 = store bf16, 1 = gelu(exact erf) -> bf16, 2 = +res -> f32
template <int BM, int BN, int WM, int WN, int EPI>
__global__ __launch_bounds__(WM*WN*64, (WM*WN == 8) ? 2 : 4)
void gemm2(const bf16* __restrict__ A, const bf16* __restrict__ BT,
           const float* __restrict__ bias, const float* __restrict__ res,
           void* __restrict__ outp, int N, int K) {
  constexpr int NT = WM * WN * 64;
  constexpr int FM = BM / WM / 16, FN = BN / WN / 16;
  constexpr int RA = (BM * 64) / (NT * 8);   // gload16 rounds for A
  constexpr int RB = (BN * 64) / (NT * 8);
  __shared__ __align__(16) bf16 sA[2][BM * 64];
  __shared__ __align__(16) bf16 sB[2][BN * 64];
  const int tid = threadIdx.x;
  const int wid = tid >> 6, lane = tid & 63;
  const int wr = wid / WN, wc = wid % WN;
  const size_t am0 = (size_t)blockIdx.x * BM;
  const size_t bn0 = (size_t)blockIdx.y * BN;

  f32x4 acc[FM][FN];
  const f32x4 fz = {0.f, 0.f, 0.f, 0.f};
#pragma unroll
  for (int m = 0; m < FM; ++m)
#pragma unroll
    for (int n = 0; n < FN; ++n) acc[m][n] = fz;

  const bf16* ag = A  + (am0 + (tid >> 3)) * (size_t)K + (tid & 7) * 8;
  const bf16* bg = BT + (bn0 + (tid >> 3)) * (size_t)K + (tid & 7) * 8;

  auto stage = [&](int bufi, int kt) {
#pragma unroll
    for (int r = 0; r < RA; ++r)
      gload16(ag + (size_t)kt * 64 + (size_t)(r * (NT / 8)) * K,
              &sA[bufi][r * NT * 8 + tid * 8]);
#pragma unroll
    for (int r = 0; r < RB; ++r)
      gload16(bg + (size_t)kt * 64 + (size_t)(r * (NT / 8)) * K,
              &sB[bufi][r * NT * 8 + tid * 8]);
  };

  const int nt = K >> 6;
  stage(0, 0);
  __syncthreads();
  int buf = 0;
  for (int t = 0; t < nt; ++t) {
    if (t + 1 < nt) stage(buf ^ 1, t + 1);   // issue next-tile loads FIRST
    const bf16* pa = sA[buf] + (wr * (BM / WM) + (lane & 15)) * 64 + (lane >> 4) * 8;
    const bf16* pb = sB[buf] + (wc * (BN / WN) + (lane & 15)) * 64 + (lane >> 4) * 8;
#pragma unroll
    for (int kk = 0; kk < 2; ++kk) {
      bf16x8 a[FM], b[FN];
#pragma unroll
      for (int m = 0; m < FM; ++m) a[m] = *(const bf16x8*)(pa + m * 16 * 64 + kk * 32);
#pragma unroll
      for (int n = 0; n < FN; ++n) b[n] = *(const bf16x8*)(pb + n * 16 * 64 + kk * 32);
#pragma unroll
      for (int m = 0; m < FM; ++m)
#pragma unroll
        for (int n = 0; n < FN; ++n)
          acc[m][n] = __builtin_amdgcn_mfma_f32_16x16x32_bf16(a[m], b[n], acc[m][n], 0, 0, 0);
    }
    __syncthreads();   // drains staged loads (vmcnt) AFTER compute issued
    buf ^= 1;
  }

#pragma unroll
  for (int n = 0; n < FN; ++n) {
    const int col = (int)bn0 + wc * (BN / WN) + n * 16 + (lane & 15);
    const float bv = bias[col];
#pragma unroll
    for (int m = 0; m < FM; ++m) {
      const int row0 = (int)am0 + wr * (BM / WM) + m * 16 + (lane >> 4) * 4;
#pragma unroll
      for (int j = 0; j < 4; ++j) {
        const size_t idx = (size_t)(row0 + j) * N + col;
        float v = acc[m][n][j] + bv;
        if constexpr (EPI == 0) {
          ((bf16*)outp)[idx] = (bf16)v;
        } else if constexpr (EPI == 1) {
          ((bf16*)outp)[idx] = (bf16)(0.5f * v * (1.0f + erff(v * 0.70710678118f)));
        } else {
          ((float*)outp)[idx] = v + res[idx];
        }
      }
    }
  }
}

// ---- flash attention (causal). Q/K/V rows have stride ld; head h at +h*64
__global__ __launch_bounds__(256) void attn_k(const bf16* __restrict__ Q,
                                              const bf16* __restrict__ Kb,
                                              const bf16* __restrict__ Vb,
                                              bf16* __restrict__ Y, int ld) {
  int bh = blockIdx.x;
  int b = bh >> 4, h = bh & 15;
  int qt = blockIdx.y;
  int q0 = qt * 64;
  int tid = threadIdx.x, wid = tid >> 6, lane = tid & 63;

  __shared__ __align__(16) bf16 sK[64 * 64];
  __shared__ __align__(16) bf16 sVT[64 * 64];
  __shared__ __align__(16) bf16 sP[4][16 * 64];

  const size_t rowQ = (size_t)(b * T_ + q0 + wid * 16 + (lane & 15)) * ld + h * 64 + (lane >> 4) * 8;
  bf16x8 qf0 = *(const bf16x8*)(Q + rowQ);
  bf16x8 qf1 = *(const bf16x8*)(Q + rowQ + 32);

  float m_run[4] = {-1e30f, -1e30f, -1e30f, -1e30f};
  float l_run[4] = {0.f, 0.f, 0.f, 0.f};
  const f32x4 fz = {0.f, 0.f, 0.f, 0.f};
  f32x4 o[4];
#pragma unroll
  for (int i = 0; i < 4; ++i) o[i] = fz;

  const bf16* kg = Kb + (size_t)(b * T_ + wid * 16 + (lane >> 3)) * ld + h * 64 + (lane & 7) * 8;
  bf16* lk = sK + (wid * 16) * 64;

  for (int kt = 0; kt <= qt; ++kt) {
    int k0 = kt * 64;
#pragma unroll
    for (int i = 0; i < 2; ++i)
      gload16(kg + ((size_t)(k0 + i * 8)) * ld, lk + i * 8 * 64);
#pragma unroll
    for (int c = 0; c < 2; ++c) {
      int ch = tid + 256 * c;           // 0..511
      int r = ch >> 3, sl = ch & 7;
      bf16x8 vv = *(const bf16x8*)(Vb + (size_t)(b * T_ + k0 + r) * ld + h * 64 + sl * 8);
#pragma unroll
      for (int j = 0; j < 8; ++j)
        sVT[(sl * 8 + j) * 64 + r] = vv[j];
    }
    __syncthreads();

    f32x4 s[4];
#pragma unroll
    for (int ni = 0; ni < 4; ++ni) {
      bf16x8 kf0 = *(const bf16x8*)(sK + (ni * 16 + (lane & 15)) * 64 + (lane >> 4) * 8);
      bf16x8 kf1 = *(const bf16x8*)(sK + (ni * 16 + (lane & 15)) * 64 + 32 + (lane >> 4) * 8);
      f32x4 t = fz;
      t = __builtin_amdgcn_mfma_f32_16x16x32_bf16(qf0, kf0, t, 0, 0, 0);
      t = __builtin_amdgcn_mfma_f32_16x16x32_bf16(qf1, kf1, t, 0, 0, 0);
      s[ni] = t;
    }

    int rbase = q0 + wid * 16 + (lane >> 4) * 4;
    int cbase = k0 + (lane & 15);
    float tm[4] = {-1e30f, -1e30f, -1e30f, -1e30f};
#pragma unroll
    for (int ni = 0; ni < 4; ++ni)
#pragma unroll
      for (int j = 0; j < 4; ++j) {
        float v = s[ni][j] * 0.125f;
        if (cbase + ni * 16 > rbase + j) v = -1e30f;   // causal mask
        s[ni][j] = v;
        tm[j] = fmaxf(tm[j], v);
      }
#pragma unroll
    for (int j = 0; j < 4; ++j)
#pragma unroll
      for (int mk = 1; mk < 16; mk <<= 1)
        tm[j] = fmaxf(tm[j], __shfl_xor(tm[j], mk));

    float fac[4], rs[4] = {0.f, 0.f, 0.f, 0.f};
#pragma unroll
    for (int j = 0; j < 4; ++j) {
      float mn = fmaxf(m_run[j], tm[j]);
      fac[j] = __expf(m_run[j] - mn);
      m_run[j] = mn;
    }
#pragma unroll
    for (int ni = 0; ni < 4; ++ni)
#pragma unroll
      for (int j = 0; j < 4; ++j) {
        float p = __expf(s[ni][j] - m_run[j]);
        rs[j] += p;
        sP[wid][((lane >> 4) * 4 + j) * 64 + ni * 16 + (lane & 15)] = (bf16)p;
      }
#pragma unroll
    for (int j = 0; j < 4; ++j) {
#pragma unroll
      for (int mk = 1; mk < 16; mk <<= 1)
        rs[j] += __shfl_xor(rs[j], mk);
      l_run[j] = l_run[j] * fac[j] + rs[j];
    }
#pragma unroll
    for (int df = 0; df < 4; ++df)
#pragma unroll
      for (int j = 0; j < 4; ++j)
        o[df][j] *= fac[j];
    __syncthreads();

#pragma unroll
    for (int kk = 0; kk < 2; ++kk) {
      bf16x8 pf = *(const bf16x8*)(sP[wid] + (lane & 15) * 64 + kk * 32 + (lane >> 4) * 8);
#pragma unroll
      for (int df = 0; df < 4; ++df) {
        bf16x8 vf = *(const bf16x8*)(sVT + (df * 16 + (lane & 15)) * 64 + kk * 32 + (lane >> 4) * 8);
        o[df] = __builtin_amdgcn_mfma_f32_16x16x32_bf16(pf, vf, o[df], 0, 0, 0);
      }
    }
    __syncthreads();
  }

#pragma unroll
  for (int df = 0; df < 4; ++df)
#pragma unroll
    for (int j = 0; j < 4; ++j) {
      int row = q0 + wid * 16 + (lane >> 4) * 4 + j;
      int d = df * 16 + (lane & 15);
      Y[(size_t)(b * T_ + row) * C_ + h * 64 + d] = (bf16)(o[df][j] / l_run[j]);
    }
}

extern "C" void kernel_launch(void* const* d_in, const int* in_sizes, int n_in,
                              void* d_out, int out_size, void* d_ws, size_t ws_size,
                              hipStream_t stream) {
  (void)in_sizes; (void)n_in; (void)out_size; (void)ws_size;
  const float* x    = (const float*)d_in[0];
  const float* ln1g = (const float*)d_in[1];
  const float* ln1b = (const float*)d_in[2];
  const float* wq   = (const float*)d_in[3];
  const float* bq   = (const float*)d_in[4];
  const float* wk   = (const float*)d_in[5];
  const float* bk   = (const float*)d_in[6];
  const float* wv   = (const float*)d_in[7];
  const float* bv   = (const float*)d_in[8];
  const float* wo   = (const float*)d_in[9];
  const float* bo   = (const float*)d_in[10];
  const float* ln2g = (const float*)d_in[11];
  const float* ln2b = (const float*)d_in[12];
  const float* w1   = (const float*)d_in[13];
  const float* b1   = (const float*)d_in[14];
  const float* w2   = (const float*)d_in[15];
  const float* b2   = (const float*)d_in[16];

  char* ws = (char*)d_ws;
  const size_t MB = 1024 * 1024;
  bf16* WqkvT = (bf16*)(ws +  0 * MB);   // 6 MB  (3072 x 1024)
  bf16* WoT   = (bf16*)(ws +  6 * MB);   // 2 MB
  bf16* W1T   = (bf16*)(ws +  8 * MB);   // 8 MB
  bf16* W2T   = (bf16*)(ws + 16 * MB);   // 8 MB
  bf16* hbuf  = (bf16*)(ws + 24 * MB);   // 8 MB (ln1 out; reused for ln2 out)
  bf16* qkv   = (bf16*)(ws + 32 * MB);   // 24 MB (4096 x 3072)
  bf16* yb    = (bf16*)(ws + 56 * MB);   // 8 MB
  bf16* mb    = (bf16*)(ws + 32 * MB);   // 32 MB, reuses qkv+yb (dead by then)
  float* x1   = (float*)(ws + 64 * MB);  // 16 MB     -> total 80 MB
  float* bqkv = (float*)d_out;           // 12 KB scratch; d_out rewritten at end

  dim3 blk(256);
  wconvT<<<dim3(32, 32),  blk, 0, stream>>>(wq, WqkvT,                 1024, 1024);
  wconvT<<<dim3(32, 32),  blk, 0, stream>>>(wk, WqkvT + 1024 * 1024,   1024, 1024);
  wconvT<<<dim3(32, 32),  blk, 0, stream>>>(wv, WqkvT + 2048 * 1024,   1024, 1024);
  wconvT<<<dim3(32, 32),  blk, 0, stream>>>(wo, WoT, 1024, 1024);
  wconvT<<<dim3(128, 32), blk, 0, stream>>>(w1, W1T, 1024, 4096);
  wconvT<<<dim3(32, 128), blk, 0, stream>>>(w2, W2T, 4096, 1024);
  bcat<<<12, blk, 0, stream>>>(bq, bk, bv, bqkv);

  ln_k<<<M_, blk, 0, stream>>>(x, ln1g, ln1b, hbuf);
  gemm2<128,128,2,2,0><<<dim3(32, 24), 256, 0, stream>>>(hbuf, WqkvT, bqkv, nullptr, qkv, 3072, 1024);
  attn_k<<<dim3(64, 16), blk, 0, stream>>>(qkv, qkv + 1024, qkv + 2048, yb, 3072);
  gemm2<128,128,2,2,2><<<dim3(32, 8),  256, 0, stream>>>(yb, WoT, bo, x, x1, 1024, 1024);
  ln_k<<<M_, blk, 0, stream>>>(x1, ln2g, ln2b, hbuf);
  gemm2<256,256,2,4,1><<<dim3(16, 16), 512, 0, stream>>>(hbuf, W1T, b1, nullptr, mb, 4096, 1024);
  gemm2<128,128,2,2,2><<<dim3(32, 8),  256, 0, stream>>>(mb, W2T, b2, x1, (float*)d_out, 1024, 4096);
}

// Round 3
// 338.167 us; speedup vs baseline: 1.0601x; 1.0095x over previous
//
#include <hip/hip_runtime.h>
#include <hip/hip_bf16.h>
#include <math.h>

#define B_ 4
#define T_ 1024
#define C_ 1024
#define H_ 16
#define D_ 64
#define M_ (B_*T_)   /* 4096 rows */

typedef __bf16 bf16;
typedef __bf16 bf16x8 __attribute__((ext_vector_type(8)));
typedef float  f32x4  __attribute__((ext_vector_type(4)));

__device__ __forceinline__ void gload16(const void* g, void* l) {
  __builtin_amdgcn_global_load_lds((const __attribute__((address_space(1))) void*)g,
                                   (__attribute__((address_space(3))) void*)l,
                                   16, 0, 0);
}

// ---- weight transpose + fp32->bf16 convert: W (K x N) f32  ->  WT (N x K) bf16
__global__ __launch_bounds__(256) void wconvT(const float* __restrict__ W,
                                              bf16* __restrict__ WT, int K, int N) {
  __shared__ float tile[32][33];
  int n0 = blockIdx.x * 32, k0 = blockIdx.y * 32;
  int tx = threadIdx.x & 31, ty = threadIdx.x >> 5;  // 32 x 8
#pragma unroll
  for (int i = ty; i < 32; i += 8)
    tile[i][tx] = W[(size_t)(k0 + i) * N + n0 + tx];
  __syncthreads();
#pragma unroll
  for (int i = ty; i < 32; i += 8)
    WT[(size_t)(n0 + i) * K + k0 + tx] = (bf16)tile[tx][i];
}

// ---- concat three 1024-f32 bias vectors
__global__ __launch_bounds__(256) void bcat(const float* __restrict__ a,
                                            const float* __restrict__ b,
                                            const float* __restrict__ c,
                                            float* __restrict__ o) {
  int i = blockIdx.x * 256 + threadIdx.x;  // 0..3071
  o[i] = (i < 1024) ? a[i] : ((i < 2048) ? b[i - 1024] : c[i - 2048]);
}

// ---- LayerNorm: x (rows x 1024) f32 -> out bf16
__global__ __launch_bounds__(256) void ln_k(const float* __restrict__ x,
                                            const float* __restrict__ g,
                                            const float* __restrict__ b,
                                            bf16* __restrict__ out) {
  int row = blockIdx.x;
  int t = threadIdx.x;
  float4 xv = ((const float4*)(x + (size_t)row * C_))[t];
  float s  = xv.x + xv.y + xv.z + xv.w;
  float ss = xv.x*xv.x + xv.y*xv.y + xv.z*xv.z + xv.w*xv.w;
#pragma unroll
  for (int m = 32; m; m >>= 1) { s += __shfl_xor(s, m); ss += __shfl_xor(ss, m); }
  __shared__ float red[8];
  int wid = t >> 6;
  if ((t & 63) == 0) { red[wid] = s; red[4 + wid] = ss; }
  __syncthreads();
  s  = red[0] + red[1] + red[2] + red[3];
  ss = red[4] + red[5] + red[6] + red[7];
  float mean = s * (1.0f / C_);
  float var  = ss * (1.0f / C_) - mean * mean;
  float inv  = rsqrtf(var + 1e-5f);
  float4 gv = ((const float4*)g)[t];
  float4 bv = ((const float4*)b)[t];
  bf16* o = out + (size_t)row * C_ + t * 4;
  o[0] = (bf16)((xv.x - mean) * inv * gv.x + bv.x);
  o[1] = (bf16)((xv.y - mean) * inv * gv.y + bv.y);
  o[2] = (bf16)((xv.z - mean) * inv * gv.z + bv.z);
  o[3] = (bf16)((xv.w - mean) * inv * gv.w + bv.w);
}

// ---- 2-phase double-buffered GEMM: out = epi(A @ BT^T + bias [+ res])
// A: (M x K) bf16 row-major.  BT: (N x K) bf16 row-major.  K % 64 == 0.
// EPI: 0 = store bf16, 1 = gelu(exact erf) -> bf16, 2 = +res -> f32
// 128x128 tile, 256 thr, 64KB LDS -> 2 blocks/CU (guide: 128^2 is the right
// tile for simple 2-barrier loops; 256^2 needs the 8-phase schedule).
template <int BM, int BN, int WM, int WN, int EPI>
__global__ __launch_bounds__(WM*WN*64, 2)
void gemm2(const bf16* __restrict__ A, const bf16* __restrict__ BT,
           const float* __restrict__ bias, const float* __restrict__ res,
           void* __restrict__ outp, int N, int K) {
  constexpr int NT = WM * WN * 64;
  constexpr int FM = BM / WM / 16, FN = BN / WN / 16;
  constexpr int RA = (BM * 64) / (NT * 8);   // gload16 rounds for A
  constexpr int RB = (BN * 64) / (NT * 8);
  __shared__ __align__(16) bf16 sA[2][BM * 64];
  __shared__ __align__(16) bf16 sB[2][BN * 64];
  const int tid = threadIdx.x;
  const int wid = tid >> 6, lane = tid & 63;
  const int wr = wid / WN, wc = wid % WN;
  const size_t am0 = (size_t)blockIdx.x * BM;
  const size_t bn0 = (size_t)blockIdx.y * BN;

  f32x4 acc[FM][FN];
  const f32x4 fz = {0.f, 0.f, 0.f, 0.f};
#pragma unroll
  for (int m = 0; m < FM; ++m)
#pragma unroll
    for (int n = 0; n < FN; ++n) acc[m][n] = fz;

  const bf16* ag = A  + (am0 + (tid >> 3)) * (size_t)K + (tid & 7) * 8;
  const bf16* bg = BT + (bn0 + (tid >> 3)) * (size_t)K + (tid & 7) * 8;

  auto stage = [&](int bufi, int kt) {
#pragma unroll
    for (int r = 0; r < RA; ++r)
      gload16(ag + (size_t)kt * 64 + (size_t)(r * (NT / 8)) * K,
              &sA[bufi][r * NT * 8 + tid * 8]);
#pragma unroll
    for (int r = 0; r < RB; ++r)
      gload16(bg + (size_t)kt * 64 + (size_t)(r * (NT / 8)) * K,
              &sB[bufi][r * NT * 8 + tid * 8]);
  };

  const int nt = K >> 6;
  stage(0, 0);
  __syncthreads();
  int buf = 0;
  for (int t = 0; t < nt; ++t) {
    if (t + 1 < nt) stage(buf ^ 1, t + 1);   // issue next-tile loads FIRST
    const bf16* pa = sA[buf] + (wr * (BM / WM) + (lane & 15)) * 64 + (lane >> 4) * 8;
    const bf16* pb = sB[buf] + (wc * (BN / WN) + (lane & 15)) * 64 + (lane >> 4) * 8;
#pragma unroll
    for (int kk = 0; kk < 2; ++kk) {
      bf16x8 a[FM], b[FN];
#pragma unroll
      for (int m = 0; m < FM; ++m) a[m] = *(const bf16x8*)(pa + m * 16 * 64 + kk * 32);
#pragma unroll
      for (int n = 0; n < FN; ++n) b[n] = *(const bf16x8*)(pb + n * 16 * 64 + kk * 32);
#pragma unroll
      for (int m = 0; m < FM; ++m)
#pragma unroll
        for (int n = 0; n < FN; ++n)
          acc[m][n] = __builtin_amdgcn_mfma_f32_16x16x32_bf16(a[m], b[n], acc[m][n], 0, 0, 0);
    }
    __syncthreads();   // drains staged loads (vmcnt) AFTER compute issued
    buf ^= 1;
  }

#pragma unroll
  for (int n = 0; n < FN; ++n) {
    const int col = (int)bn0 + wc * (BN / WN) + n * 16 + (lane & 15);
    const float bv = bias[col];
#pragma unroll
    for (int m = 0; m < FM; ++m) {
      const int row0 = (int)am0 + wr * (BM / WM) + m * 16 + (lane >> 4) * 4;
#pragma unroll
      for (int j = 0; j < 4; ++j) {
        const size_t idx = (size_t)(row0 + j) * N + col;
        float v = acc[m][n][j] + bv;
        if constexpr (EPI == 0) {
          ((bf16*)outp)[idx] = (bf16)v;
        } else if constexpr (EPI == 1) {
          ((bf16*)outp)[idx] = (bf16)(0.5f * v * (1.0f + erff(v * 0.70710678118f)));
        } else {
          ((float*)outp)[idx] = v + res[idx];
        }
      }
    }
  }
}

// ---- flash attention (causal). Q/K/V rows have stride ld; head h at +h*64
__global__ __launch_bounds__(256) void attn_k(const bf16* __restrict__ Q,
                                              const bf16* __restrict__ Kb,
                                              const bf16* __restrict__ Vb,
                                              bf16* __restrict__ Y, int ld) {
  int bh = blockIdx.x;
  int b = bh >> 4, h = bh & 15;
  int qt = blockIdx.y;
  int q0 = qt * 64;
  int tid = threadIdx.x, wid = tid >> 6, lane = tid & 63;

  __shared__ __align__(16) bf16 sK[64 * 64];
  __shared__ __align__(16) bf16 sVT[64 * 64];
  __shared__ __align__(16) bf16 sP[4][16 * 64];

  const size_t rowQ = (size_t)(b * T_ + q0 + wid * 16 + (lane & 15)) * ld + h * 64 + (lane >> 4) * 8;
  bf16x8 qf0 = *(const bf16x8*)(Q + rowQ);
  bf16x8 qf1 = *(const bf16x8*)(Q + rowQ + 32);

  float m_run[4] = {-1e30f, -1e30f, -1e30f, -1e30f};
  float l_run[4] = {0.f, 0.f, 0.f, 0.f};
  const f32x4 fz = {0.f, 0.f, 0.f, 0.f};
  f32x4 o[4];
#pragma unroll
  for (int i = 0; i < 4; ++i) o[i] = fz;

  const bf16* kg = Kb + (size_t)(b * T_ + wid * 16 + (lane >> 3)) * ld + h * 64 + (lane & 7) * 8;
  bf16* lk = sK + (wid * 16) * 64;

  for (int kt = 0; kt <= qt; ++kt) {
    int k0 = kt * 64;
#pragma unroll
    for (int i = 0; i < 2; ++i)
      gload16(kg + ((size_t)(k0 + i * 8)) * ld, lk + i * 8 * 64);
#pragma unroll
    for (int c = 0; c < 2; ++c) {
      int ch = tid + 256 * c;           // 0..511
      int r = ch >> 3, sl = ch & 7;
      bf16x8 vv = *(const bf16x8*)(Vb + (size_t)(b * T_ + k0 + r) * ld + h * 64 + sl * 8);
#pragma unroll
      for (int j = 0; j < 8; ++j)
        sVT[(sl * 8 + j) * 64 + r] = vv[j];
    }
    __syncthreads();

    f32x4 s[4];
#pragma unroll
    for (int ni = 0; ni < 4; ++ni) {
      bf16x8 kf0 = *(const bf16x8*)(sK + (ni * 16 + (lane & 15)) * 64 + (lane >> 4) * 8);
      bf16x8 kf1 = *(const bf16x8*)(sK + (ni * 16 + (lane & 15)) * 64 + 32 + (lane >> 4) * 8);
      f32x4 t = fz;
      t = __builtin_amdgcn_mfma_f32_16x16x32_bf16(qf0, kf0, t, 0, 0, 0);
      t = __builtin_amdgcn_mfma_f32_16x16x32_bf16(qf1, kf1, t, 0, 0, 0);
      s[ni] = t;
    }

    int rbase = q0 + wid * 16 + (lane >> 4) * 4;
    int cbase = k0 + (lane & 15);
    float tm[4] = {-1e30f, -1e30f, -1e30f, -1e30f};
#pragma unroll
    for (int ni = 0; ni < 4; ++ni)
#pragma unroll
      for (int j = 0; j < 4; ++j) {
        float v = s[ni][j] * 0.125f;
        if (cbase + ni * 16 > rbase + j) v = -1e30f;   // causal mask
        s[ni][j] = v;
        tm[j] = fmaxf(tm[j], v);
      }
#pragma unroll
    for (int j = 0; j < 4; ++j)
#pragma unroll
      for (int mk = 1; mk < 16; mk <<= 1)
        tm[j] = fmaxf(tm[j], __shfl_xor(tm[j], mk));

    float fac[4], rs[4] = {0.f, 0.f, 0.f, 0.f};
#pragma unroll
    for (int j = 0; j < 4; ++j) {
      float mn = fmaxf(m_run[j], tm[j]);
      fac[j] = __expf(m_run[j] - mn);
      m_run[j] = mn;
    }
#pragma unroll
    for (int ni = 0; ni < 4; ++ni)
#pragma unroll
      for (int j = 0; j < 4; ++j) {
        float p = __expf(s[ni][j] - m_run[j]);
        rs[j] += p;
        sP[wid][((lane >> 4) * 4 + j) * 64 + ni * 16 + (lane & 15)] = (bf16)p;
      }
#pragma unroll
    for (int j = 0; j < 4; ++j) {
#pragma unroll
      for (int mk = 1; mk < 16; mk <<= 1)
        rs[j] += __shfl_xor(rs[j], mk);
      l_run[j] = l_run[j] * fac[j] + rs[j];
    }
#pragma unroll
    for (int df = 0; df < 4; ++df)
#pragma unroll
      for (int j = 0; j < 4; ++j)
        o[df][j] *= fac[j];
    __syncthreads();

#pragma unroll
    for (int kk = 0; kk < 2; ++kk) {
      bf16x8 pf = *(const bf16x8*)(sP[wid] + (lane & 15) * 64 + kk * 32 + (lane >> 4) * 8);
#pragma unroll
      for (int df = 0; df < 4; ++df) {
        bf16x8 vf = *(const bf16x8*)(sVT + (df * 16 + (lane & 15)) * 64 + kk * 32 + (lane >> 4) * 8);
        o[df] = __builtin_amdgcn_mfma_f32_16x16x32_bf16(pf, vf, o[df], 0, 0, 0);
      }
    }
    __syncthreads();
  }

#pragma unroll
  for (int df = 0; df < 4; ++df)
#pragma unroll
    for (int j = 0; j < 4; ++j) {
      int row = q0 + wid * 16 + (lane >> 4) * 4 + j;
      int d = df * 16 + (lane & 15);
      Y[(size_t)(b * T_ + row) * C_ + h * 64 + d] = (bf16)(o[df][j] / l_run[j]);
    }
}

extern "C" void kernel_launch(void* const* d_in, const int* in_sizes, int n_in,
                              void* d_out, int out_size, void* d_ws, size_t ws_size,
                              hipStream_t stream) {
  (void)in_sizes; (void)n_in; (void)out_size; (void)ws_size;
  const float* x    = (const float*)d_in[0];
  const float* ln1g = (const float*)d_in[1];
  const float* ln1b = (const float*)d_in[2];
  const float* wq   = (const float*)d_in[3];
  const float* bq   = (const float*)d_in[4];
  const float* wk   = (const float*)d_in[5];
  const float* bk   = (const float*)d_in[6];
  const float* wv   = (const float*)d_in[7];
  const float* bv   = (const float*)d_in[8];
  const float* wo   = (const float*)d_in[9];
  const float* bo   = (const float*)d_in[10];
  const float* ln2g = (const float*)d_in[11];
  const float* ln2b = (const float*)d_in[12];
  const float* w1   = (const float*)d_in[13];
  const float* b1   = (const float*)d_in[14];
  const float* w2   = (const float*)d_in[15];
  const float* b2   = (const float*)d_in[16];

  char* ws = (char*)d_ws;
  const size_t MB = 1024 * 1024;
  bf16* WqkvT = (bf16*)(ws +  0 * MB);   // 6 MB  (3072 x 1024)
  bf16* WoT   = (bf16*)(ws +  6 * MB);   // 2 MB
  bf16* W1T   = (bf16*)(ws +  8 * MB);   // 8 MB
  bf16* W2T   = (bf16*)(ws + 16 * MB);   // 8 MB
  bf16* hbuf  = (bf16*)(ws + 24 * MB);   // 8 MB (ln1 out; reused for ln2 out)
  bf16* qkv   = (bf16*)(ws + 32 * MB);   // 24 MB (4096 x 3072)
  bf16* yb    = (bf16*)(ws + 56 * MB);   // 8 MB
  bf16* mb    = (bf16*)(ws + 32 * MB);   // 32 MB, reuses qkv+yb (dead by then)
  float* x1   = (float*)(ws + 64 * MB);  // 16 MB     -> total 80 MB
  float* bqkv = (float*)d_out;           // 12 KB scratch; d_out rewritten at end

  dim3 blk(256);
  wconvT<<<dim3(32, 32),  blk, 0, stream>>>(wq, WqkvT,                 1024, 1024);
  wconvT<<<dim3(32, 32),  blk, 0, stream>>>(wk, WqkvT + 1024 * 1024,   1024, 1024);
  wconvT<<<dim3(32, 32),  blk, 0, stream>>>(wv, WqkvT + 2048 * 1024,   1024, 1024);
  wconvT<<<dim3(32, 32),  blk, 0, stream>>>(wo, WoT, 1024, 1024);
  wconvT<<<dim3(128, 32), blk, 0, stream>>>(w1, W1T, 1024, 4096);
  wconvT<<<dim3(32, 128), blk, 0, stream>>>(w2, W2T, 4096, 1024);
  bcat<<<12, blk, 0, stream>>>(bq, bk, bv, bqkv);

  ln_k<<<M_, blk, 0, stream>>>(x, ln1g, ln1b, hbuf);
  gemm2<128,128,2,2,0><<<dim3(32, 24), 256, 0, stream>>>(hbuf, WqkvT, bqkv, nullptr, qkv, 3072, 1024);
  attn_k<<<dim3(64, 16), blk, 0, stream>>>(qkv, qkv + 1024, qkv + 2048, yb, 3072);
  gemm2<128,128,2,2,2><<<dim3(32, 8),  256, 0, stream>>>(yb, WoT, bo, x, x1, 1024, 1024);
  ln_k<<<M_, blk, 0, stream>>>(x1, ln2g, ln2b, hbuf);
  gemm2<128,128,2,2,1><<<dim3(32, 32), 256, 0, stream>>>(hbuf, W1T, b1, nullptr, mb, 4096, 1024);
  gemm2<128,128,2,2,2><<<dim3(32, 8),  256, 0, stream>>>(mb, W2T, b2, x1, (float*)d_out, 1024, 4096);
}

// Round 4
// 334.026 us; speedup vs baseline: 1.0733x; 1.0124x over previous
//
#include <hip/hip_runtime.h>
#include <hip/hip_bf16.h>
#include <math.h>

#define B_ 4
#define T_ 1024
#define C_ 1024
#define H_ 16
#define D_ 64
#define M_ (B_*T_)   /* 4096 rows */

typedef __bf16 bf16;
typedef __bf16 bf16x8 __attribute__((ext_vector_type(8)));
typedef float  f32x4  __attribute__((ext_vector_type(4)));

#define MFMA16(a, b, c) __builtin_amdgcn_mfma_f32_16x16x32_bf16((a), (b), (c), 0, 0, 0)

__device__ __forceinline__ void gload16(const void* g, void* l) {
  __builtin_amdgcn_global_load_lds((const __attribute__((address_space(1))) void*)g,
                                   (__attribute__((address_space(3))) void*)l,
                                   16, 0, 0);
}

// ---- weight transpose + fp32->bf16 convert: W (K x N) f32  ->  WT (N x K) bf16
__global__ __launch_bounds__(256) void wconvT(const float* __restrict__ W,
                                              bf16* __restrict__ WT, int K, int N) {
  __shared__ float tile[32][33];
  int n0 = blockIdx.x * 32, k0 = blockIdx.y * 32;
  int tx = threadIdx.x & 31, ty = threadIdx.x >> 5;  // 32 x 8
#pragma unroll
  for (int i = ty; i < 32; i += 8)
    tile[i][tx] = W[(size_t)(k0 + i) * N + n0 + tx];
  __syncthreads();
#pragma unroll
  for (int i = ty; i < 32; i += 8)
    WT[(size_t)(n0 + i) * K + k0 + tx] = (bf16)tile[tx][i];
}

// ---- concat three 1024-f32 bias vectors
__global__ __launch_bounds__(256) void bcat(const float* __restrict__ a,
                                            const float* __restrict__ b,
                                            const float* __restrict__ c,
                                            float* __restrict__ o) {
  int i = blockIdx.x * 256 + threadIdx.x;  // 0..3071
  o[i] = (i < 1024) ? a[i] : ((i < 2048) ? b[i - 1024] : c[i - 2048]);
}

// ---- LayerNorm: x (rows x 1024) f32 -> out bf16
__global__ __launch_bounds__(256) void ln_k(const float* __restrict__ x,
                                            const float* __restrict__ g,
                                            const float* __restrict__ b,
                                            bf16* __restrict__ out) {
  int row = blockIdx.x;
  int t = threadIdx.x;
  float4 xv = ((const float4*)(x + (size_t)row * C_))[t];
  float s  = xv.x + xv.y + xv.z + xv.w;
  float ss = xv.x*xv.x + xv.y*xv.y + xv.z*xv.z + xv.w*xv.w;
#pragma unroll
  for (int m = 32; m; m >>= 1) { s += __shfl_xor(s, m); ss += __shfl_xor(ss, m); }
  __shared__ float red[8];
  int wid = t >> 6;
  if ((t & 63) == 0) { red[wid] = s; red[4 + wid] = ss; }
  __syncthreads();
  s  = red[0] + red[1] + red[2] + red[3];
  ss = red[4] + red[5] + red[6] + red[7];
  float mean = s * (1.0f / C_);
  float var  = ss * (1.0f / C_) - mean * mean;
  float inv  = rsqrtf(var + 1e-5f);
  float4 gv = ((const float4*)g)[t];
  float4 bv = ((const float4*)b)[t];
  bf16* o = out + (size_t)row * C_ + t * 4;
  o[0] = (bf16)((xv.x - mean) * inv * gv.x + bv.x);
  o[1] = (bf16)((xv.y - mean) * inv * gv.y + bv.y);
  o[2] = (bf16)((xv.z - mean) * inv * gv.z + bv.z);
  o[3] = (bf16)((xv.w - mean) * inv * gv.w + bv.w);
}

// ============================================================================
// 8-phase 256x256 GEMM (T3+T4+T5): out = epi(A @ BT^T + bias), bf16 out.
// A: (M x K) bf16. BT: (N x K) bf16. K % 64 == 0. 512 thr = 8 waves (2Mx4N).
// Per wave: 128x64 output = acc[8][4]. LDS 128KB: 2 dbuf x (A 32KB + B 32KB).
// Per K-tile, 4 phases; phase p issues half-tile p of tile t+1 (2 gloads);
// counted vmcnt(2) before the closing barrier of phases 0 and 3 (never 0).
// EPI: 0 = bf16 store, 1 = gelu(exact erf) -> bf16.  Epilogue staged via LDS
// for coalesced dwordx4 stores.
// ============================================================================
template <int EPI>
__global__ __launch_bounds__(512, 2)
void gemm8(const bf16* __restrict__ A, const bf16* __restrict__ BT,
           const float* __restrict__ bias, bf16* __restrict__ outp,
           int N, int K) {
  __shared__ __align__(16) bf16 smem[65536];   // 128 KiB
  const int tid = threadIdx.x;
  const int lane = tid & 63, wid = tid >> 6;
  const int wr = wid >> 2, wc = wid & 3;
  const size_t am0 = (size_t)blockIdx.x * 256;
  const size_t bn0 = (size_t)blockIdx.y * 256;

  f32x4 acc[8][4];
  const f32x4 fz = {0.f, 0.f, 0.f, 0.f};
#pragma unroll
  for (int m = 0; m < 8; ++m)
#pragma unroll
    for (int n = 0; n < 4; ++n) acc[m][n] = fz;

  // staging addresses: thread covers row tid>>3 (+64 per round), col (tid&7)*8
  const bf16* ag = A  + (am0 + (tid >> 3)) * (size_t)K + (tid & 7) * 8;
  const bf16* bg = BT + (bn0 + (tid >> 3)) * (size_t)K + (tid & 7) * 8;
  const int ldst = tid * 8;  // element offset inside a 64-row region (16B/lane)

  auto issueA = [&](int b, int t, int h) {   // A half h: rows h*128..h*128+127
#pragma unroll
    for (int r = 0; r < 2; ++r)
      gload16(ag + ((size_t)(h * 128 + r * 64)) * K + t * 64,
              smem + b * 16384 + h * 8192 + r * 4096 + ldst);
  };
  auto issueB = [&](int b, int t, int h) {
#pragma unroll
    for (int r = 0; r < 2; ++r)
      gload16(bg + ((size_t)(h * 128 + r * 64)) * K + t * 64,
              smem + 32768 + b * 16384 + h * 8192 + r * 4096 + ldst);
  };

  const int arow = lane & 15, asel = (lane >> 4) * 8;
  const int nt = K >> 6;

  // ---- prologue: tile 0 -> buf 0 (issue order h0=A0,h1=A1,h2=B0,h3=B1)
  issueA(0, 0, 0); issueA(0, 0, 1); issueB(0, 0, 0); issueB(0, 0, 1);
  asm volatile("s_waitcnt vmcnt(2)" ::: "memory");   // h0,h1,h2 landed
  __builtin_amdgcn_s_barrier();

  for (int t = 0; t < nt; ++t) {
    const int cb = t & 1, nb = cb ^ 1;
    const bool pf = (t + 1) < nt;
    const bf16* pa = smem + cb * 16384 + (wr * 128 + arow) * 64 + asel;
    const bf16* pb = smem + 32768 + cb * 16384 + (wc * 64 + arow) * 64 + asel;
    bf16x8 a0[8], a1[8], b0[2], b1[2];

    // ---- phase 0: reads A(wr) + B half0 @kk0 ; issues A-h0(t+1) ; mfma n0,n1
#pragma unroll
    for (int m = 0; m < 8; ++m) a0[m] = *(const bf16x8*)(pa + m * 1024);
    b0[0] = *(const bf16x8*)(pb);
    b0[1] = *(const bf16x8*)(pb + 1024);
    if (pf) issueA(nb, t + 1, 0);
    __builtin_amdgcn_s_barrier();
    asm volatile("s_waitcnt lgkmcnt(0)" ::: "memory");
    __builtin_amdgcn_sched_barrier(0);
    __builtin_amdgcn_s_setprio(1);
#pragma unroll
    for (int m = 0; m < 8; ++m) {
      acc[m][0] = MFMA16(a0[m], b0[0], acc[m][0]);
      acc[m][1] = MFMA16(a0[m], b0[1], acc[m][1]);
    }
    __builtin_amdgcn_s_setprio(0);
    asm volatile("s_waitcnt vmcnt(2)" ::: "memory");  // t's B-h1 in (for phase 1)
    __builtin_amdgcn_s_barrier();

    // ---- phase 1: reads B half1 @kk0 ; issues A-h1(t+1) ; mfma n2,n3
    b1[0] = *(const bf16x8*)(pb + 2048);
    b1[1] = *(const bf16x8*)(pb + 3072);
    if (pf) issueA(nb, t + 1, 1);
    __builtin_amdgcn_s_barrier();
    asm volatile("s_waitcnt lgkmcnt(0)" ::: "memory");
    __builtin_amdgcn_sched_barrier(0);
    __builtin_amdgcn_s_setprio(1);
#pragma unroll
    for (int m = 0; m < 8; ++m) {
      acc[m][2] = MFMA16(a0[m], b1[0], acc[m][2]);
      acc[m][3] = MFMA16(a0[m], b1[1], acc[m][3]);
    }
    __builtin_amdgcn_s_setprio(0);
    __builtin_amdgcn_s_barrier();

    // ---- phase 2: reads A(wr) + B half0 @kk1 ; issues B-h0(t+1) ; mfma n0,n1
#pragma unroll
    for (int m = 0; m < 8; ++m) a1[m] = *(const bf16x8*)(pa + m * 1024 + 32);
    b0[0] = *(const bf16x8*)(pb + 32);
    b0[1] = *(const bf16x8*)(pb + 1024 + 32);
    if (pf) issueB(nb, t + 1, 0);
    __builtin_amdgcn_s_barrier();
    asm volatile("s_waitcnt lgkmcnt(0)" ::: "memory");
    __builtin_amdgcn_sched_barrier(0);
    __builtin_amdgcn_s_setprio(1);
#pragma unroll
    for (int m = 0; m < 8; ++m) {
      acc[m][0] = MFMA16(a1[m], b0[0], acc[m][0]);
      acc[m][1] = MFMA16(a1[m], b0[1], acc[m][1]);
    }
    __builtin_amdgcn_s_setprio(0);
    __builtin_amdgcn_s_barrier();

    // ---- phase 3: reads B half1 @kk1 ; issues B-h1(t+1) ; mfma n2,n3
    b1[0] = *(const bf16x8*)(pb + 2048 + 32);
    b1[1] = *(const bf16x8*)(pb + 3072 + 32);
    if (pf) issueB(nb, t + 1, 1);
    __builtin_amdgcn_s_barrier();
    asm volatile("s_waitcnt lgkmcnt(0)" ::: "memory");
    __builtin_amdgcn_sched_barrier(0);
    __builtin_amdgcn_s_setprio(1);
#pragma unroll
    for (int m = 0; m < 8; ++m) {
      acc[m][2] = MFMA16(a1[m], b1[0], acc[m][2]);
      acc[m][3] = MFMA16(a1[m], b1[1], acc[m][3]);
    }
    __builtin_amdgcn_s_setprio(0);
    asm volatile("s_waitcnt vmcnt(2)" ::: "memory");  // t+1's h0,h1,h2 in
    __builtin_amdgcn_s_barrier();
  }

  // ---- epilogue: bias (+gelu), stage bf16 tile in LDS, coalesced stores
  __syncthreads();
#pragma unroll
  for (int m = 0; m < 8; ++m) {
    const int row = wr * 128 + m * 16 + (lane >> 4) * 4;
#pragma unroll
    for (int n = 0; n < 4; ++n) {
      const int col = wc * 64 + n * 16 + (lane & 15);
      const float bv = bias[bn0 + col];
#pragma unroll
      for (int j = 0; j < 4; ++j) {
        float v = acc[m][n][j] + bv;
        if constexpr (EPI == 1) v = 0.5f * v * (1.0f + erff(v * 0.70710678118f));
        smem[(row + j) * 256 + col] = (bf16)v;
      }
    }
  }
  __syncthreads();
#pragma unroll
  for (int i = 0; i < 16; ++i) {
    const int idx = i * 512 + tid;
    const int row = idx >> 5, c8 = (idx & 31) * 8;
    *(bf16x8*)(outp + (am0 + row) * N + bn0 + c8) =
        *(const bf16x8*)(smem + row * 256 + c8);
  }
}

// ---- 2-phase double-buffered GEMM (128x128): out = A @ BT^T + bias + res (f32)
template <int BM, int BN, int WM, int WN, int EPI>
__global__ __launch_bounds__(WM*WN*64, 2)
void gemm2(const bf16* __restrict__ A, const bf16* __restrict__ BT,
           const float* __restrict__ bias, const float* __restrict__ res,
           void* __restrict__ outp, int N, int K) {
  constexpr int NT = WM * WN * 64;
  constexpr int FM = BM / WM / 16, FN = BN / WN / 16;
  constexpr int RA = (BM * 64) / (NT * 8);
  constexpr int RB = (BN * 64) / (NT * 8);
  __shared__ __align__(16) bf16 sA[2][BM * 64];
  __shared__ __align__(16) bf16 sB[2][BN * 64];
  const int tid = threadIdx.x;
  const int wid = tid >> 6, lane = tid & 63;
  const int wr = wid / WN, wc = wid % WN;
  const size_t am0 = (size_t)blockIdx.x * BM;
  const size_t bn0 = (size_t)blockIdx.y * BN;

  f32x4 acc[FM][FN];
  const f32x4 fz = {0.f, 0.f, 0.f, 0.f};
#pragma unroll
  for (int m = 0; m < FM; ++m)
#pragma unroll
    for (int n = 0; n < FN; ++n) acc[m][n] = fz;

  const bf16* ag = A  + (am0 + (tid >> 3)) * (size_t)K + (tid & 7) * 8;
  const bf16* bg = BT + (bn0 + (tid >> 3)) * (size_t)K + (tid & 7) * 8;

  auto stage = [&](int bufi, int kt) {
#pragma unroll
    for (int r = 0; r < RA; ++r)
      gload16(ag + (size_t)kt * 64 + (size_t)(r * (NT / 8)) * K,
              &sA[bufi][r * NT * 8 + tid * 8]);
#pragma unroll
    for (int r = 0; r < RB; ++r)
      gload16(bg + (size_t)kt * 64 + (size_t)(r * (NT / 8)) * K,
              &sB[bufi][r * NT * 8 + tid * 8]);
  };

  const int nt = K >> 6;
  stage(0, 0);
  __syncthreads();
  int buf = 0;
  for (int t = 0; t < nt; ++t) {
    if (t + 1 < nt) stage(buf ^ 1, t + 1);
    const bf16* pa = sA[buf] + (wr * (BM / WM) + (lane & 15)) * 64 + (lane >> 4) * 8;
    const bf16* pb = sB[buf] + (wc * (BN / WN) + (lane & 15)) * 64 + (lane >> 4) * 8;
#pragma unroll
    for (int kk = 0; kk < 2; ++kk) {
      bf16x8 a[FM], b[FN];
#pragma unroll
      for (int m = 0; m < FM; ++m) a[m] = *(const bf16x8*)(pa + m * 16 * 64 + kk * 32);
#pragma unroll
      for (int n = 0; n < FN; ++n) b[n] = *(const bf16x8*)(pb + n * 16 * 64 + kk * 32);
#pragma unroll
      for (int m = 0; m < FM; ++m)
#pragma unroll
        for (int n = 0; n < FN; ++n)
          acc[m][n] = MFMA16(a[m], b[n], acc[m][n]);
    }
    __syncthreads();
    buf ^= 1;
  }

#pragma unroll
  for (int n = 0; n < FN; ++n) {
    const int col = (int)bn0 + wc * (BN / WN) + n * 16 + (lane & 15);
    const float bv = bias[col];
#pragma unroll
    for (int m = 0; m < FM; ++m) {
      const int row0 = (int)am0 + wr * (BM / WM) + m * 16 + (lane >> 4) * 4;
#pragma unroll
      for (int j = 0; j < 4; ++j) {
        const size_t idx = (size_t)(row0 + j) * N + col;
        float v = acc[m][n][j] + bv;
        if constexpr (EPI == 0) {
          ((bf16*)outp)[idx] = (bf16)v;
        } else if constexpr (EPI == 1) {
          ((bf16*)outp)[idx] = (bf16)(0.5f * v * (1.0f + erff(v * 0.70710678118f)));
        } else {
          ((float*)outp)[idx] = v + res[idx];
        }
      }
    }
  }
}

// ---- flash attention (causal). Q/K/V rows have stride ld; head h at +h*64
__global__ __launch_bounds__(256) void attn_k(const bf16* __restrict__ Q,
                                              const bf16* __restrict__ Kb,
                                              const bf16* __restrict__ Vb,
                                              bf16* __restrict__ Y, int ld) {
  int bh = blockIdx.x;
  int b = bh >> 4, h = bh & 15;
  int qt = blockIdx.y;
  int q0 = qt * 64;
  int tid = threadIdx.x, wid = tid >> 6, lane = tid & 63;

  __shared__ __align__(16) bf16 sK[64 * 64];
  __shared__ __align__(16) bf16 sVT[64 * 64];
  __shared__ __align__(16) bf16 sP[4][16 * 64];

  const size_t rowQ = (size_t)(b * T_ + q0 + wid * 16 + (lane & 15)) * ld + h * 64 + (lane >> 4) * 8;
  bf16x8 qf0 = *(const bf16x8*)(Q + rowQ);
  bf16x8 qf1 = *(const bf16x8*)(Q + rowQ + 32);

  float m_run[4] = {-1e30f, -1e30f, -1e30f, -1e30f};
  float l_run[4] = {0.f, 0.f, 0.f, 0.f};
  const f32x4 fz = {0.f, 0.f, 0.f, 0.f};
  f32x4 o[4];
#pragma unroll
  for (int i = 0; i < 4; ++i) o[i] = fz;

  const bf16* kg = Kb + (size_t)(b * T_ + wid * 16 + (lane >> 3)) * ld + h * 64 + (lane & 7) * 8;
  bf16* lk = sK + (wid * 16) * 64;

  for (int kt = 0; kt <= qt; ++kt) {
    int k0 = kt * 64;
#pragma unroll
    for (int i = 0; i < 2; ++i)
      gload16(kg + ((size_t)(k0 + i * 8)) * ld, lk + i * 8 * 64);
#pragma unroll
    for (int c = 0; c < 2; ++c) {
      int ch = tid + 256 * c;           // 0..511
      int r = ch >> 3, sl = ch & 7;
      bf16x8 vv = *(const bf16x8*)(Vb + (size_t)(b * T_ + k0 + r) * ld + h * 64 + sl * 8);
#pragma unroll
      for (int j = 0; j < 8; ++j)
        sVT[(sl * 8 + j) * 64 + r] = vv[j];
    }
    __syncthreads();

    f32x4 s[4];
#pragma unroll
    for (int ni = 0; ni < 4; ++ni) {
      bf16x8 kf0 = *(const bf16x8*)(sK + (ni * 16 + (lane & 15)) * 64 + (lane >> 4) * 8);
      bf16x8 kf1 = *(const bf16x8*)(sK + (ni * 16 + (lane & 15)) * 64 + 32 + (lane >> 4) * 8);
      f32x4 t = fz;
      t = MFMA16(qf0, kf0, t);
      t = MFMA16(qf1, kf1, t);
      s[ni] = t;
    }

    int rbase = q0 + wid * 16 + (lane >> 4) * 4;
    int cbase = k0 + (lane & 15);
    float tm[4] = {-1e30f, -1e30f, -1e30f, -1e30f};
#pragma unroll
    for (int ni = 0; ni < 4; ++ni)
#pragma unroll
      for (int j = 0; j < 4; ++j) {
        float v = s[ni][j] * 0.125f;
        if (cbase + ni * 16 > rbase + j) v = -1e30f;   // causal mask
        s[ni][j] = v;
        tm[j] = fmaxf(tm[j], v);
      }
#pragma unroll
    for (int j = 0; j < 4; ++j)
#pragma unroll
      for (int mk = 1; mk < 16; mk <<= 1)
        tm[j] = fmaxf(tm[j], __shfl_xor(tm[j], mk));

    float fac[4], rs[4] = {0.f, 0.f, 0.f, 0.f};
#pragma unroll
    for (int j = 0; j < 4; ++j) {
      float mn = fmaxf(m_run[j], tm[j]);
      fac[j] = __expf(m_run[j] - mn);
      m_run[j] = mn;
    }
#pragma unroll
    for (int ni = 0; ni < 4; ++ni)
#pragma unroll
      for (int j = 0; j < 4; ++j) {
        float p = __expf(s[ni][j] - m_run[j]);
        rs[j] += p;
        sP[wid][((lane >> 4) * 4 + j) * 64 + ni * 16 + (lane & 15)] = (bf16)p;
      }
#pragma unroll
    for (int j = 0; j < 4; ++j) {
#pragma unroll
      for (int mk = 1; mk < 16; mk <<= 1)
        rs[j] += __shfl_xor(rs[j], mk);
      l_run[j] = l_run[j] * fac[j] + rs[j];
    }
#pragma unroll
    for (int df = 0; df < 4; ++df)
#pragma unroll
      for (int j = 0; j < 4; ++j)
        o[df][j] *= fac[j];
    __syncthreads();

#pragma unroll
    for (int kk = 0; kk < 2; ++kk) {
      bf16x8 pf = *(const bf16x8*)(sP[wid] + (lane & 15) * 64 + kk * 32 + (lane >> 4) * 8);
#pragma unroll
      for (int df = 0; df < 4; ++df) {
        bf16x8 vf = *(const bf16x8*)(sVT + (df * 16 + (lane & 15)) * 64 + kk * 32 + (lane >> 4) * 8);
        o[df] = MFMA16(pf, vf, o[df]);
      }
    }
    __syncthreads();
  }

#pragma unroll
  for (int df = 0; df < 4; ++df)
#pragma unroll
    for (int j = 0; j < 4; ++j) {
      int row = q0 + wid * 16 + (lane >> 4) * 4 + j;
      int d = df * 16 + (lane & 15);
      Y[(size_t)(b * T_ + row) * C_ + h * 64 + d] = (bf16)(o[df][j] / l_run[j]);
    }
}

extern "C" void kernel_launch(void* const* d_in, const int* in_sizes, int n_in,
                              void* d_out, int out_size, void* d_ws, size_t ws_size,
                              hipStream_t stream) {
  (void)in_sizes; (void)n_in; (void)out_size; (void)ws_size;
  const float* x    = (const float*)d_in[0];
  const float* ln1g = (const float*)d_in[1];
  const float* ln1b = (const float*)d_in[2];
  const float* wq   = (const float*)d_in[3];
  const float* bq   = (const float*)d_in[4];
  const float* wk   = (const float*)d_in[5];
  const float* bk   = (const float*)d_in[6];
  const float* wv   = (const float*)d_in[7];
  const float* bv   = (const float*)d_in[8];
  const float* wo   = (const float*)d_in[9];
  const float* bo   = (const float*)d_in[10];
  const float* ln2g = (const float*)d_in[11];
  const float* ln2b = (const float*)d_in[12];
  const float* w1   = (const float*)d_in[13];
  const float* b1   = (const float*)d_in[14];
  const float* w2   = (const float*)d_in[15];
  const float* b2   = (const float*)d_in[16];

  char* ws = (char*)d_ws;
  const size_t MB = 1024 * 1024;
  bf16* WqkvT = (bf16*)(ws +  0 * MB);   // 6 MB  (3072 x 1024)
  bf16* WoT   = (bf16*)(ws +  6 * MB);   // 2 MB
  bf16* W1T   = (bf16*)(ws +  8 * MB);   // 8 MB
  bf16* W2T   = (bf16*)(ws + 16 * MB);   // 8 MB
  bf16* hbuf  = (bf16*)(ws + 24 * MB);   // 8 MB (ln1 out; reused for ln2 out)
  bf16* qkv   = (bf16*)(ws + 32 * MB);   // 24 MB (4096 x 3072)
  bf16* yb    = (bf16*)(ws + 56 * MB);   // 8 MB
  bf16* mb    = (bf16*)(ws + 32 * MB);   // 32 MB, reuses qkv+yb (dead by then)
  float* x1   = (float*)(ws + 64 * MB);  // 16 MB     -> total 80 MB
  float* bqkv = (float*)d_out;           // 12 KB scratch; d_out rewritten at end

  dim3 blk(256);
  wconvT<<<dim3(32, 32),  blk, 0, stream>>>(wq, WqkvT,                 1024, 1024);
  wconvT<<<dim3(32, 32),  blk, 0, stream>>>(wk, WqkvT + 1024 * 1024,   1024, 1024);
  wconvT<<<dim3(32, 32),  blk, 0, stream>>>(wv, WqkvT + 2048 * 1024,   1024, 1024);
  wconvT<<<dim3(32, 32),  blk, 0, stream>>>(wo, WoT, 1024, 1024);
  wconvT<<<dim3(128, 32), blk, 0, stream>>>(w1, W1T, 1024, 4096);
  wconvT<<<dim3(32, 128), blk, 0, stream>>>(w2, W2T, 4096, 1024);
  bcat<<<12, blk, 0, stream>>>(bq, bk, bv, bqkv);

  ln_k<<<M_, blk, 0, stream>>>(x, ln1g, ln1b, hbuf);
  gemm8<0><<<dim3(16, 12), 512, 0, stream>>>(hbuf, WqkvT, bqkv, qkv, 3072, 1024);
  attn_k<<<dim3(64, 16), blk, 0, stream>>>(qkv, qkv + 1024, qkv + 2048, yb, 3072);
  gemm2<128,128,2,2,2><<<dim3(32, 8),  256, 0, stream>>>(yb, WoT, bo, x, x1, 1024, 1024);
  ln_k<<<M_, blk, 0, stream>>>(x1, ln2g, ln2b, hbuf);
  gemm8<1><<<dim3(16, 16), 512, 0, stream>>>(hbuf, W1T, b1, mb, 4096, 1024);
  gemm2<128,128,2,2,2><<<dim3(32, 8),  256, 0, stream>>>(mb, W2T, b2, x1, (float*)d_out, 1024, 4096);
}

// Round 5
// 318.825 us; speedup vs baseline: 1.1244x; 1.0477x over previous
//
#include <hip/hip_runtime.h>
#include <hip/hip_bf16.h>
#include <math.h>

#define B_ 4
#define T_ 1024
#define C_ 1024
#define H_ 16
#define D_ 64
#define M_ (B_*T_)   /* 4096 rows */

typedef __bf16 bf16;
typedef __bf16 bf16x8 __attribute__((ext_vector_type(8)));
typedef float  f32x4  __attribute__((ext_vector_type(4)));

#define MFMA16(a, b, c) __builtin_amdgcn_mfma_f32_16x16x32_bf16((a), (b), (c), 0, 0, 0)

__device__ __forceinline__ void gload16(const void* g, void* l) {
  __builtin_amdgcn_global_load_lds((const __attribute__((address_space(1))) void*)g,
                                   (__attribute__((address_space(3))) void*)l,
                                   16, 0, 0);
}

// ---- weight transpose + fp32->bf16 convert: W (K x N) f32  ->  WT (N x K) bf16
__global__ __launch_bounds__(256) void wconvT(const float* __restrict__ W,
                                              bf16* __restrict__ WT, int K, int N) {
  __shared__ float tile[32][33];
  int n0 = blockIdx.x * 32, k0 = blockIdx.y * 32;
  int tx = threadIdx.x & 31, ty = threadIdx.x >> 5;  // 32 x 8
#pragma unroll
  for (int i = ty; i < 32; i += 8)
    tile[i][tx] = W[(size_t)(k0 + i) * N + n0 + tx];
  __syncthreads();
#pragma unroll
  for (int i = ty; i < 32; i += 8)
    WT[(size_t)(n0 + i) * K + k0 + tx] = (bf16)tile[tx][i];
}

// ---- concat three 1024-f32 bias vectors
__global__ __launch_bounds__(256) void bcat(const float* __restrict__ a,
                                            const float* __restrict__ b,
                                            const float* __restrict__ c,
                                            float* __restrict__ o) {
  int i = blockIdx.x * 256 + threadIdx.x;  // 0..3071
  o[i] = (i < 1024) ? a[i] : ((i < 2048) ? b[i - 1024] : c[i - 2048]);
}

// ---- LayerNorm: x (rows x 1024) f32 -> out bf16
__global__ __launch_bounds__(256) void ln_k(const float* __restrict__ x,
                                            const float* __restrict__ g,
                                            const float* __restrict__ b,
                                            bf16* __restrict__ out) {
  int row = blockIdx.x;
  int t = threadIdx.x;
  float4 xv = ((const float4*)(x + (size_t)row * C_))[t];
  float s  = xv.x + xv.y + xv.z + xv.w;
  float ss = xv.x*xv.x + xv.y*xv.y + xv.z*xv.z + xv.w*xv.w;
#pragma unroll
  for (int m = 32; m; m >>= 1) { s += __shfl_xor(s, m); ss += __shfl_xor(ss, m); }
  __shared__ float red[8];
  int wid = t >> 6;
  if ((t & 63) == 0) { red[wid] = s; red[4 + wid] = ss; }
  __syncthreads();
  s  = red[0] + red[1] + red[2] + red[3];
  ss = red[4] + red[5] + red[6] + red[7];
  float mean = s * (1.0f / C_);
  float var  = ss * (1.0f / C_) - mean * mean;
  float inv  = rsqrtf(var + 1e-5f);
  float4 gv = ((const float4*)g)[t];
  float4 bv = ((const float4*)b)[t];
  bf16* o = out + (size_t)row * C_ + t * 4;
  o[0] = (bf16)((xv.x - mean) * inv * gv.x + bv.x);
  o[1] = (bf16)((xv.y - mean) * inv * gv.y + bv.y);
  o[2] = (bf16)((xv.z - mean) * inv * gv.z + bv.z);
  o[3] = (bf16)((xv.w - mean) * inv * gv.w + bv.w);
}

// ============================================================================
// 8-phase 256x256 GEMM, K-split halves + T2 swizzle + T4 counted vmcnt + T5.
// A: (M x K) bf16. BT: (N x K) bf16. K % 64 == 0. 512 thr = 8 waves (2Mx4N).
// LDS 128KB = 2buf x { A: 2 kk-half x [256 rows x 32 cols], B: same }.
// Rows are 64B; physical chunk j = logical chunk c XOR ((row>>1)&3)  -> 8-lane
// read groups hit 8 distinct 16B granules (conflict-free). global_load_lds
// writes linearly; the SOURCE column carries the same XOR (involution).
// Phases 0-1 consume kk0 halves only, 2-3 kk1 -> two vmcnt(4) waits per tile
// (never 0 while prefetching).  Invariant: at each wait, outstanding = the 4
// loads of the next tile's 2 issued halves; everything older has landed.
// EPI: 0 = bf16 store, 1 = gelu(exact erf) -> bf16.
// ============================================================================
template <int EPI>
__global__ __launch_bounds__(512, 2)
void gemm8(const bf16* __restrict__ A, const bf16* __restrict__ BT,
           const float* __restrict__ bias, bf16* __restrict__ outp,
           int N, int K) {
  __shared__ __align__(16) bf16 smem[65536];   // 128 KiB
  const int tid = threadIdx.x;
  const int lane = tid & 63, wid = tid >> 6;
  const int wr = wid >> 2, wc = wid & 3;
  const size_t am0 = (size_t)blockIdx.x * 256;
  const size_t bn0 = (size_t)blockIdx.y * 256;

  f32x4 acc[8][4];
  const f32x4 fz = {0.f, 0.f, 0.f, 0.f};
#pragma unroll
  for (int m = 0; m < 8; ++m)
#pragma unroll
    for (int n = 0; n < 4; ++n) acc[m][n] = fz;

  // -- staging: thread covers (row = tid>>2 [+128/round], chunk = tid&3).
  //    source column chunk pre-XORed with ((row>>1)&3) = ((tid>>3)&3).
  const int schunk = ((tid & 3) ^ ((tid >> 3) & 3)) * 8;
  const bf16* ag = A  + (am0 + (tid >> 2)) * (size_t)K + schunk;
  const bf16* bg = BT + (bn0 + (tid >> 2)) * (size_t)K + schunk;

  auto issueA = [&](int b, int t, int h) {   // A kk-half h of tile t -> buf b
#pragma unroll
    for (int r = 0; r < 2; ++r)
      gload16(ag + (size_t)t * 64 + h * 32 + (size_t)(r * 128) * K,
              smem + b * 16384 + h * 8192 + r * 4096 + tid * 8);
  };
  auto issueB = [&](int b, int t, int h) {
#pragma unroll
    for (int r = 0; r < 2; ++r)
      gload16(bg + (size_t)t * 64 + h * 32 + (size_t)(r * 128) * K,
              smem + 32768 + b * 16384 + h * 8192 + r * 4096 + tid * 8);
  };

  const int arow = lane & 15;
  const int joff = (((lane >> 4) ^ ((lane >> 1) & 3))) * 8;  // swizzled chunk
  const int nt = K >> 6;

  // ---- prologue: tile 0, issue order A-k0, B-k0, A-k1, B-k1 (8 loads)
  issueA(0, 0, 0); issueB(0, 0, 0); issueA(0, 0, 1); issueB(0, 0, 1);
  asm volatile("s_waitcnt vmcnt(4)" ::: "memory");   // A-k0, B-k0 landed
  __builtin_amdgcn_s_barrier();

  for (int t = 0; t < nt; ++t) {
    const int cb = t & 1, nb = cb ^ 1;
    const bool pf = (t + 1) < nt;
    const bf16* paB = smem + cb * 16384 + (wr * 128 + arow) * 32 + joff;
    const bf16* pbB = smem + 32768 + cb * 16384 + (wc * 64 + arow) * 32 + joff;
    bf16x8 a0[8], a1[8], bq0, bq1;

    // ---- phase 0: read A-kk0 + B-kk0(n0,n1); issue A-k0(t+1); mfma n0,n1
#pragma unroll
    for (int m = 0; m < 8; ++m) a0[m] = *(const bf16x8*)(paB + m * 512);
    bq0 = *(const bf16x8*)(pbB);
    bq1 = *(const bf16x8*)(pbB + 512);
    if (pf) issueA(nb, t + 1, 0);
    __builtin_amdgcn_s_barrier();
    asm volatile("s_waitcnt lgkmcnt(0)" ::: "memory");
    __builtin_amdgcn_sched_barrier(0);
    __builtin_amdgcn_s_setprio(1);
#pragma unroll
    for (int m = 0; m < 8; ++m) {
      acc[m][0] = MFMA16(a0[m], bq0, acc[m][0]);
      acc[m][1] = MFMA16(a0[m], bq1, acc[m][1]);
    }
    __builtin_amdgcn_s_setprio(0);
    __builtin_amdgcn_s_barrier();

    // ---- phase 1: read B-kk0(n2,n3); issue B-k0(t+1); mfma n2,n3
    bq0 = *(const bf16x8*)(pbB + 1024);
    bq1 = *(const bf16x8*)(pbB + 1536);
    if (pf) issueB(nb, t + 1, 0);
    __builtin_amdgcn_s_barrier();
    asm volatile("s_waitcnt lgkmcnt(0)" ::: "memory");
    __builtin_amdgcn_sched_barrier(0);
    __builtin_amdgcn_s_setprio(1);
#pragma unroll
    for (int m = 0; m < 8; ++m) {
      acc[m][2] = MFMA16(a0[m], bq0, acc[m][2]);
      acc[m][3] = MFMA16(a0[m], bq1, acc[m][3]);
    }
    __builtin_amdgcn_s_setprio(0);
    // wait: tile t's kk1 halves landed (outstanding = t+1's A-k0,B-k0 = 4)
    if (pf) asm volatile("s_waitcnt vmcnt(4)" ::: "memory");
    else    asm volatile("s_waitcnt vmcnt(0)" ::: "memory");
    __builtin_amdgcn_s_barrier();

    // ---- phase 2: read A-kk1 + B-kk1(n0,n1); issue A-k1(t+1); mfma n0,n1
#pragma unroll
    for (int m = 0; m < 8; ++m) a1[m] = *(const bf16x8*)(paB + 8192 + m * 512);
    bq0 = *(const bf16x8*)(pbB + 8192);
    bq1 = *(const bf16x8*)(pbB + 8192 + 512);
    if (pf) issueA(nb, t + 1, 1);
    __builtin_amdgcn_s_barrier();
    asm volatile("s_waitcnt lgkmcnt(0)" ::: "memory");
    __builtin_amdgcn_sched_barrier(0);
    __builtin_amdgcn_s_setprio(1);
#pragma unroll
    for (int m = 0; m < 8; ++m) {
      acc[m][0] = MFMA16(a1[m], bq0, acc[m][0]);
      acc[m][1] = MFMA16(a1[m], bq1, acc[m][1]);
    }
    __builtin_amdgcn_s_setprio(0);
    __builtin_amdgcn_s_barrier();

    // ---- phase 3: read B-kk1(n2,n3); issue B-k1(t+1); mfma n2,n3
    bq0 = *(const bf16x8*)(pbB + 8192 + 1024);
    bq1 = *(const bf16x8*)(pbB + 8192 + 1536);
    if (pf) issueB(nb, t + 1, 1);
    __builtin_amdgcn_s_barrier();
    asm volatile("s_waitcnt lgkmcnt(0)" ::: "memory");
    __builtin_amdgcn_sched_barrier(0);
    __builtin_amdgcn_s_setprio(1);
#pragma unroll
    for (int m = 0; m < 8; ++m) {
      acc[m][2] = MFMA16(a1[m], bq0, acc[m][2]);
      acc[m][3] = MFMA16(a1[m], bq1, acc[m][3]);
    }
    __builtin_amdgcn_s_setprio(0);
    // wait: t+1's kk0 halves landed (outstanding = t+1's A-k1,B-k1 = 4)
    if (pf) asm volatile("s_waitcnt vmcnt(4)" ::: "memory");
    else    asm volatile("s_waitcnt vmcnt(0)" ::: "memory");
    __builtin_amdgcn_s_barrier();
  }

  // ---- epilogue: bias (+gelu), stage bf16 tile in LDS, coalesced stores
  __syncthreads();
#pragma unroll
  for (int m = 0; m < 8; ++m) {
    const int row = wr * 128 + m * 16 + (lane >> 4) * 4;
#pragma unroll
    for (int n = 0; n < 4; ++n) {
      const int col = wc * 64 + n * 16 + (lane & 15);
      const float bv = bias[bn0 + col];
#pragma unroll
      for (int j = 0; j < 4; ++j) {
        float v = acc[m][n][j] + bv;
        if constexpr (EPI == 1) v = 0.5f * v * (1.0f + erff(v * 0.70710678118f));
        smem[(row + j) * 256 + col] = (bf16)v;
      }
    }
  }
  __syncthreads();
#pragma unroll
  for (int i = 0; i < 16; ++i) {
    const int idx = i * 512 + tid;
    const int row = idx >> 5, c8 = (idx & 31) * 8;
    *(bf16x8*)(outp + (am0 + row) * N + bn0 + c8) =
        *(const bf16x8*)(smem + row * 256 + c8);
  }
}

// ---- 2-phase double-buffered GEMM (128x128): out = A @ BT^T + bias [+res]
template <int BM, int BN, int WM, int WN, int EPI>
__global__ __launch_bounds__(WM*WN*64, 2)
void gemm2(const bf16* __restrict__ A, const bf16* __restrict__ BT,
           const float* __restrict__ bias, const float* __restrict__ res,
           void* __restrict__ outp, int N, int K) {
  constexpr int NT = WM * WN * 64;
  constexpr int FM = BM / WM / 16, FN = BN / WN / 16;
  constexpr int RA = (BM * 64) / (NT * 8);
  constexpr int RB = (BN * 64) / (NT * 8);
  __shared__ __align__(16) bf16 sA[2][BM * 64];
  __shared__ __align__(16) bf16 sB[2][BN * 64];
  const int tid = threadIdx.x;
  const int wid = tid >> 6, lane = tid & 63;
  const int wr = wid / WN, wc = wid % WN;
  const size_t am0 = (size_t)blockIdx.x * BM;
  const size_t bn0 = (size_t)blockIdx.y * BN;

  f32x4 acc[FM][FN];
  const f32x4 fz = {0.f, 0.f, 0.f, 0.f};
#pragma unroll
  for (int m = 0; m < FM; ++m)
#pragma unroll
    for (int n = 0; n < FN; ++n) acc[m][n] = fz;

  const bf16* ag = A  + (am0 + (tid >> 3)) * (size_t)K + (tid & 7) * 8;
  const bf16* bg = BT + (bn0 + (tid >> 3)) * (size_t)K + (tid & 7) * 8;

  auto stage = [&](int bufi, int kt) {
#pragma unroll
    for (int r = 0; r < RA; ++r)
      gload16(ag + (size_t)kt * 64 + (size_t)(r * (NT / 8)) * K,
              &sA[bufi][r * NT * 8 + tid * 8]);
#pragma unroll
    for (int r = 0; r < RB; ++r)
      gload16(bg + (size_t)kt * 64 + (size_t)(r * (NT / 8)) * K,
              &sB[bufi][r * NT * 8 + tid * 8]);
  };

  const int nt = K >> 6;
  stage(0, 0);
  __syncthreads();
  int buf = 0;
  for (int t = 0; t < nt; ++t) {
    if (t + 1 < nt) stage(buf ^ 1, t + 1);
    const bf16* pa = sA[buf] + (wr * (BM / WM) + (lane & 15)) * 64 + (lane >> 4) * 8;
    const bf16* pb = sB[buf] + (wc * (BN / WN) + (lane & 15)) * 64 + (lane >> 4) * 8;
#pragma unroll
    for (int kk = 0; kk < 2; ++kk) {
      bf16x8 a[FM], b[FN];
#pragma unroll
      for (int m = 0; m < FM; ++m) a[m] = *(const bf16x8*)(pa + m * 16 * 64 + kk * 32);
#pragma unroll
      for (int n = 0; n < FN; ++n) b[n] = *(const bf16x8*)(pb + n * 16 * 64 + kk * 32);
#pragma unroll
      for (int m = 0; m < FM; ++m)
#pragma unroll
        for (int n = 0; n < FN; ++n)
          acc[m][n] = MFMA16(a[m], b[n], acc[m][n]);
    }
    __syncthreads();
    buf ^= 1;
  }

#pragma unroll
  for (int n = 0; n < FN; ++n) {
    const int col = (int)bn0 + wc * (BN / WN) + n * 16 + (lane & 15);
    const float bv = bias[col];
#pragma unroll
    for (int m = 0; m < FM; ++m) {
      const int row0 = (int)am0 + wr * (BM / WM) + m * 16 + (lane >> 4) * 4;
#pragma unroll
      for (int j = 0; j < 4; ++j) {
        const size_t idx = (size_t)(row0 + j) * N + col;
        float v = acc[m][n][j] + bv;
        if constexpr (EPI == 0) {
          ((bf16*)outp)[idx] = (bf16)v;
        } else if constexpr (EPI == 1) {
          ((bf16*)outp)[idx] = (bf16)(0.5f * v * (1.0f + erff(v * 0.70710678118f)));
        } else {
          ((float*)outp)[idx] = v + res[idx];
        }
      }
    }
  }
}

// ---- flash attention (causal). Q/K/V rows have stride ld; head h at +h*64
__global__ __launch_bounds__(256) void attn_k(const bf16* __restrict__ Q,
                                              const bf16* __restrict__ Kb,
                                              const bf16* __restrict__ Vb,
                                              bf16* __restrict__ Y, int ld) {
  int bh = blockIdx.x;
  int b = bh >> 4, h = bh & 15;
  int qt = blockIdx.y;
  int q0 = qt * 64;
  int tid = threadIdx.x, wid = tid >> 6, lane = tid & 63;

  __shared__ __align__(16) bf16 sK[64 * 64];
  __shared__ __align__(16) bf16 sVT[64 * 64];
  __shared__ __align__(16) bf16 sP[4][16 * 64];

  const size_t rowQ = (size_t)(b * T_ + q0 + wid * 16 + (lane & 15)) * ld + h * 64 + (lane >> 4) * 8;
  bf16x8 qf0 = *(const bf16x8*)(Q + rowQ);
  bf16x8 qf1 = *(const bf16x8*)(Q + rowQ + 32);

  float m_run[4] = {-1e30f, -1e30f, -1e30f, -1e30f};
  float l_run[4] = {0.f, 0.f, 0.f, 0.f};
  const f32x4 fz = {0.f, 0.f, 0.f, 0.f};
  f32x4 o[4];
#pragma unroll
  for (int i = 0; i < 4; ++i) o[i] = fz;

  const bf16* kg = Kb + (size_t)(b * T_ + wid * 16 + (lane >> 3)) * ld + h * 64 + (lane & 7) * 8;
  bf16* lk = sK + (wid * 16) * 64;

  for (int kt = 0; kt <= qt; ++kt) {
    int k0 = kt * 64;
#pragma unroll
    for (int i = 0; i < 2; ++i)
      gload16(kg + ((size_t)(k0 + i * 8)) * ld, lk + i * 8 * 64);
#pragma unroll
    for (int c = 0; c < 2; ++c) {
      int ch = tid + 256 * c;           // 0..511
      int r = ch >> 3, sl = ch & 7;
      bf16x8 vv = *(const bf16x8*)(Vb + (size_t)(b * T_ + k0 + r) * ld + h * 64 + sl * 8);
#pragma unroll
      for (int j = 0; j < 8; ++j)
        sVT[(sl * 8 + j) * 64 + r] = vv[j];
    }
    __syncthreads();

    f32x4 s[4];
#pragma unroll
    for (int ni = 0; ni < 4; ++ni) {
      bf16x8 kf0 = *(const bf16x8*)(sK + (ni * 16 + (lane & 15)) * 64 + (lane >> 4) * 8);
      bf16x8 kf1 = *(const bf16x8*)(sK + (ni * 16 + (lane & 15)) * 64 + 32 + (lane >> 4) * 8);
      f32x4 t = fz;
      t = MFMA16(qf0, kf0, t);
      t = MFMA16(qf1, kf1, t);
      s[ni] = t;
    }

    int rbase = q0 + wid * 16 + (lane >> 4) * 4;
    int cbase = k0 + (lane & 15);
    float tm[4] = {-1e30f, -1e30f, -1e30f, -1e30f};
#pragma unroll
    for (int ni = 0; ni < 4; ++ni)
#pragma unroll
      for (int j = 0; j < 4; ++j) {
        float v = s[ni][j] * 0.125f;
        if (cbase + ni * 16 > rbase + j) v = -1e30f;   // causal mask
        s[ni][j] = v;
        tm[j] = fmaxf(tm[j], v);
      }
#pragma unroll
    for (int j = 0; j < 4; ++j)
#pragma unroll
      for (int mk = 1; mk < 16; mk <<= 1)
        tm[j] = fmaxf(tm[j], __shfl_xor(tm[j], mk));

    float fac[4], rs[4] = {0.f, 0.f, 0.f, 0.f};
#pragma unroll
    for (int j = 0; j < 4; ++j) {
      float mn = fmaxf(m_run[j], tm[j]);
      fac[j] = __expf(m_run[j] - mn);
      m_run[j] = mn;
    }
#pragma unroll
    for (int ni = 0; ni < 4; ++ni)
#pragma unroll
      for (int j = 0; j < 4; ++j) {
        float p = __expf(s[ni][j] - m_run[j]);
        rs[j] += p;
        sP[wid][((lane >> 4) * 4 + j) * 64 + ni * 16 + (lane & 15)] = (bf16)p;
      }
#pragma unroll
    for (int j = 0; j < 4; ++j) {
#pragma unroll
      for (int mk = 1; mk < 16; mk <<= 1)
        rs[j] += __shfl_xor(rs[j], mk);
      l_run[j] = l_run[j] * fac[j] + rs[j];
    }
#pragma unroll
    for (int df = 0; df < 4; ++df)
#pragma unroll
      for (int j = 0; j < 4; ++j)
        o[df][j] *= fac[j];
    __syncthreads();

#pragma unroll
    for (int kk = 0; kk < 2; ++kk) {
      bf16x8 pf = *(const bf16x8*)(sP[wid] + (lane & 15) * 64 + kk * 32 + (lane >> 4) * 8);
#pragma unroll
      for (int df = 0; df < 4; ++df) {
        bf16x8 vf = *(const bf16x8*)(sVT + (df * 16 + (lane & 15)) * 64 + kk * 32 + (lane >> 4) * 8);
        o[df] = MFMA16(pf, vf, o[df]);
      }
    }
    __syncthreads();
  }

#pragma unroll
  for (int df = 0; df < 4; ++df)
#pragma unroll
    for (int j = 0; j < 4; ++j) {
      int row = q0 + wid * 16 + (lane >> 4) * 4 + j;
      int d = df * 16 + (lane & 15);
      Y[(size_t)(b * T_ + row) * C_ + h * 64 + d] = (bf16)(o[df][j] / l_run[j]);
    }
}

extern "C" void kernel_launch(void* const* d_in, const int* in_sizes, int n_in,
                              void* d_out, int out_size, void* d_ws, size_t ws_size,
                              hipStream_t stream) {
  (void)in_sizes; (void)n_in; (void)out_size; (void)ws_size;
  const float* x    = (const float*)d_in[0];
  const float* ln1g = (const float*)d_in[1];
  const float* ln1b = (const float*)d_in[2];
  const float* wq   = (const float*)d_in[3];
  const float* bq   = (const float*)d_in[4];
  const float* wk   = (const float*)d_in[5];
  const float* bk   = (const float*)d_in[6];
  const float* wv   = (const float*)d_in[7];
  const float* bv   = (const float*)d_in[8];
  const float* wo   = (const float*)d_in[9];
  const float* bo   = (const float*)d_in[10];
  const float* ln2g = (const float*)d_in[11];
  const float* ln2b = (const float*)d_in[12];
  const float* w1   = (const float*)d_in[13];
  const float* b1   = (const float*)d_in[14];
  const float* w2   = (const float*)d_in[15];
  const float* b2   = (const float*)d_in[16];

  char* ws = (char*)d_ws;
  const size_t MB = 1024 * 1024;
  bf16* WqkvT = (bf16*)(ws +  0 * MB);   // 6 MB  (3072 x 1024)
  bf16* WoT   = (bf16*)(ws +  6 * MB);   // 2 MB
  bf16* W1T   = (bf16*)(ws +  8 * MB);   // 8 MB
  bf16* W2T   = (bf16*)(ws + 16 * MB);   // 8 MB
  bf16* hbuf  = (bf16*)(ws + 24 * MB);   // 8 MB (ln1 out; reused for ln2 out)
  bf16* qkv   = (bf16*)(ws + 32 * MB);   // 24 MB (4096 x 3072)
  bf16* yb    = (bf16*)(ws + 56 * MB);   // 8 MB
  bf16* mb    = (bf16*)(ws + 32 * MB);   // 32 MB, reuses qkv+yb (dead by then)
  float* x1   = (float*)(ws + 64 * MB);  // 16 MB     -> total 80 MB
  float* bqkv = (float*)d_out;           // 12 KB scratch; d_out rewritten at end

  dim3 blk(256);
  wconvT<<<dim3(32, 32),  blk, 0, stream>>>(wq, WqkvT,                 1024, 1024);
  wconvT<<<dim3(32, 32),  blk, 0, stream>>>(wk, WqkvT + 1024 * 1024,   1024, 1024);
  wconvT<<<dim3(32, 32),  blk, 0, stream>>>(wv, WqkvT + 2048 * 1024,   1024, 1024);
  wconvT<<<dim3(32, 32),  blk, 0, stream>>>(wo, WoT, 1024, 1024);
  wconvT<<<dim3(128, 32), blk, 0, stream>>>(w1, W1T, 1024, 4096);
  wconvT<<<dim3(32, 128), blk, 0, stream>>>(w2, W2T, 4096, 1024);
  bcat<<<12, blk, 0, stream>>>(bq, bk, bv, bqkv);

  ln_k<<<M_, blk, 0, stream>>>(x, ln1g, ln1b, hbuf);
  gemm8<0><<<dim3(16, 12), 512, 0, stream>>>(hbuf, WqkvT, bqkv, qkv, 3072, 1024);
  attn_k<<<dim3(64, 16), blk, 0, stream>>>(qkv, qkv + 1024, qkv + 2048, yb, 3072);
  gemm2<128,128,2,2,2><<<dim3(32, 8),  256, 0, stream>>>(yb, WoT, bo, x, x1, 1024, 1024);
  ln_k<<<M_, blk, 0, stream>>>(x1, ln2g, ln2b, hbuf);
  gemm8<1><<<dim3(16, 16), 512, 0, stream>>>(hbuf, W1T, b1, mb, 4096, 1024);
  gemm2<128,128,2,2,2><<<dim3(32, 8),  256, 0, stream>>>(mb, W2T, b2, x1, (float*)d_out, 1024, 4096);
}

// Round 6
// 267.700 us; speedup vs baseline: 1.3392x; 1.1910x over previous
//
#include <hip/hip_runtime.h>
#include <hip/hip_bf16.h>
#include <math.h>

#define B_ 4
#define T_ 1024
#define C_ 1024
#define H_ 16
#define D_ 64
#define M_ (B_*T_)   /* 4096 rows */

typedef __bf16 bf16;
typedef __bf16 bf16x8 __attribute__((ext_vector_type(8)));
typedef float  f32x4  __attribute__((ext_vector_type(4)));

#define MFMA16(a, b, c) __builtin_amdgcn_mfma_f32_16x16x32_bf16((a), (b), (c), 0, 0, 0)

__device__ __forceinline__ void gload16(const void* g, void* l) {
  __builtin_amdgcn_global_load_lds((const __attribute__((address_space(1))) void*)g,
                                   (__attribute__((address_space(3))) void*)l,
                                   16, 0, 0);
}

// ---- weight transpose + fp32->bf16 convert: W (K x N) f32  ->  WT (N x K) bf16
__global__ __launch_bounds__(256) void wconvT(const float* __restrict__ W,
                                              bf16* __restrict__ WT, int K, int N) {
  __shared__ float tile[32][33];
  int n0 = blockIdx.x * 32, k0 = blockIdx.y * 32;
  int tx = threadIdx.x & 31, ty = threadIdx.x >> 5;  // 32 x 8
#pragma unroll
  for (int i = ty; i < 32; i += 8)
    tile[i][tx] = W[(size_t)(k0 + i) * N + n0 + tx];
  __syncthreads();
#pragma unroll
  for (int i = ty; i < 32; i += 8)
    WT[(size_t)(n0 + i) * K + k0 + tx] = (bf16)tile[tx][i];
}

// ---- concat three 1024-f32 bias vectors
__global__ __launch_bounds__(256) void bcat(const float* __restrict__ a,
                                            const float* __restrict__ b,
                                            const float* __restrict__ c,
                                            float* __restrict__ o) {
  int i = blockIdx.x * 256 + threadIdx.x;  // 0..3071
  o[i] = (i < 1024) ? a[i] : ((i < 2048) ? b[i - 1024] : c[i - 2048]);
}

// ---- LayerNorm: x (rows x 1024) f32 -> out bf16
__global__ __launch_bounds__(256) void ln_k(const float* __restrict__ x,
                                            const float* __restrict__ g,
                                            const float* __restrict__ b,
                                            bf16* __restrict__ out) {
  int row = blockIdx.x;
  int t = threadIdx.x;
  float4 xv = ((const float4*)(x + (size_t)row * C_))[t];
  float s  = xv.x + xv.y + xv.z + xv.w;
  float ss = xv.x*xv.x + xv.y*xv.y + xv.z*xv.z + xv.w*xv.w;
#pragma unroll
  for (int m = 32; m; m >>= 1) { s += __shfl_xor(s, m); ss += __shfl_xor(ss, m); }
  __shared__ float red[8];
  int wid = t >> 6;
  if ((t & 63) == 0) { red[wid] = s; red[4 + wid] = ss; }
  __syncthreads();
  s  = red[0] + red[1] + red[2] + red[3];
  ss = red[4] + red[5] + red[6] + red[7];
  float mean = s * (1.0f / C_);
  float var  = ss * (1.0f / C_) - mean * mean;
  float inv  = rsqrtf(var + 1e-5f);
  float4 gv = ((const float4*)g)[t];
  float4 bv = ((const float4*)b)[t];
  bf16* o = out + (size_t)row * C_ + t * 4;
  o[0] = (bf16)((xv.x - mean) * inv * gv.x + bv.x);
  o[1] = (bf16)((xv.y - mean) * inv * gv.y + bv.y);
  o[2] = (bf16)((xv.z - mean) * inv * gv.z + bv.z);
  o[3] = (bf16)((xv.w - mean) * inv * gv.w + bv.w);
}

// ============================================================================
// m97-structure GEMM: single-buffered LDS, 2-barrier loop, HIGH CO-RESIDENCY.
// out = epi(A @ BT^T + bias [+ res]).  A:(M x K) bf16, BT:(N x K) bf16, K%64==0.
// 256 thr = 4 waves (WM x WN).  LDS = (BM+BN)*64*2B (32KB @128^2) -> 4-5
// blocks/CU; __launch_bounds__(256,4) caps VGPR<=128 for 4 blocks/CU.
// Overlap comes from co-resident blocks at different loop phases (m114),
// not from in-kernel pipelining (m97: 874 TF with exactly this shape).
// Granule XOR swizzle (proven R5): LDS rows are 64 cols (128B) = 8 x 16B
// granules; physical granule = logical ^ (row & 7).  global_load_lds writes
// linearly; the global SOURCE column carries the same involution.
// EPI: 0 = bf16 store, 1 = gelu(erf) -> bf16, 2 = f32 store + residual add.
// Epilogues staged through LDS for coalesced wide stores.
// T1: bijective chunked XCD swizzle on a 1-D grid (requires nwg % 8 == 0).
// ============================================================================
template <int BM, int BN, int WM, int WN, int EPI>
__global__ __launch_bounds__(WM*WN*64, 4)
void gemms(const bf16* __restrict__ A, const bf16* __restrict__ BT,
           const float* __restrict__ bias, const float* __restrict__ res,
           void* __restrict__ outp, int N, int K, int gx) {
  constexpr int NT = WM * WN * 64;          // 256
  constexpr int FM = BM / WM / 16, FN = BN / WN / 16;
  constexpr int RA = BM / 32, RB = BN / 32; // staging rounds (32 rows / round)
  __shared__ __align__(16) bf16 smem[(BM + BN) * 64];
  bf16* sA = smem;
  bf16* sB = smem + BM * 64;
  const int tid = threadIdx.x, lane = tid & 63, wid = tid >> 6;
  const int wr = wid / WN, wc = wid % WN;

  int bid = blockIdx.x;
  const int nwg = gridDim.x;
  if (!(nwg & 7)) bid = (bid & 7) * (nwg >> 3) + (bid >> 3);  // T1 (bijective)
  const int bx = bid % gx, by = bid / gx;
  const size_t am0 = (size_t)bx * BM, bn0 = (size_t)by * BN;

  f32x4 acc[FM][FN];
  const f32x4 fz = {0.f, 0.f, 0.f, 0.f};
#pragma unroll
  for (int m = 0; m < FM; ++m)
#pragma unroll
    for (int n = 0; n < FN; ++n) acc[m][n] = fz;

  // staging: thread -> (row = tid>>3 [+32/round], granule tid&7), source
  // column granule pre-XORed with (row&7) (row&7 == (tid>>3)&7, round-invar.)
  const int srow = tid >> 3;
  const int sg = (tid & 7) ^ (srow & 7);
  const bf16* ag = A  + (am0 + srow) * (size_t)K + sg * 8;
  const bf16* bg = BT + (bn0 + srow) * (size_t)K + sg * 8;

  const int arow = lane & 15;
  const int g0 = (((lane >> 4))     ^ (lane & 7)) * 8;  // kk=0 phys granule
  const int g1 = (((lane >> 4) + 4) ^ (lane & 7)) * 8;  // kk=1 phys granule
  const int nt = K >> 6;

  for (int t = 0; t < nt; ++t) {
#pragma unroll
    for (int r = 0; r < RA; ++r)
      gload16(ag + (size_t)t * 64 + (size_t)(r * 32) * K, sA + r * 2048 + tid * 8);
#pragma unroll
    for (int r = 0; r < RB; ++r)
      gload16(bg + (size_t)t * 64 + (size_t)(r * 32) * K, sB + r * 2048 + tid * 8);
    __syncthreads();   // drains staged loads (vmcnt 0) before compute

    const bf16* pa = sA + (wr * (BM / WM) + arow) * 64;
    const bf16* pb = sB + (wc * (BN / WN) + arow) * 64;
    bf16x8 a[FM], b[FN];
#pragma unroll
    for (int m = 0; m < FM; ++m) a[m] = *(const bf16x8*)(pa + m * 16 * 64 + g0);
#pragma unroll
    for (int n = 0; n < FN; ++n) b[n] = *(const bf16x8*)(pb + n * 16 * 64 + g0);
#pragma unroll
    for (int m = 0; m < FM; ++m)
#pragma unroll
      for (int n = 0; n < FN; ++n)
        acc[m][n] = MFMA16(a[m], b[n], acc[m][n]);
#pragma unroll
    for (int m = 0; m < FM; ++m) a[m] = *(const bf16x8*)(pa + m * 16 * 64 + g1);
#pragma unroll
    for (int n = 0; n < FN; ++n) b[n] = *(const bf16x8*)(pb + n * 16 * 64 + g1);
#pragma unroll
    for (int m = 0; m < FM; ++m)
#pragma unroll
      for (int n = 0; n < FN; ++n)
        acc[m][n] = MFMA16(a[m], b[n], acc[m][n]);
    __syncthreads();   // reads done before next stage overwrites
  }

  if constexpr (EPI != 2) {
    // ---- bf16 epilogue: acc -> LDS (XOR-swizzled granules) -> coalesced b128
#pragma unroll
    for (int m = 0; m < FM; ++m) {
      const int row0 = wr * (BM / WM) + m * 16 + (lane >> 4) * 4;
#pragma unroll
      for (int n = 0; n < FN; ++n) {
        const int col = wc * (BN / WN) + n * 16 + (lane & 15);
        const float bv = bias[bn0 + col];
#pragma unroll
        for (int j = 0; j < 4; ++j) {
          float v = acc[m][n][j] + bv;
          if constexpr (EPI == 1) v = 0.5f * v * (1.0f + erff(v * 0.70710678118f));
          const int rr = row0 + j;
          smem[rr * BN + (((col >> 3) ^ (rr & 7)) << 3) + (col & 7)] = (bf16)v;
        }
      }
    }
    __syncthreads();
    constexpr int GR = BN / 8;                 // granules per row
    constexpr int SI = BM * BN / (NT * 8);     // store iters
#pragma unroll
    for (int i = 0; i < SI; ++i) {
      const int idx = i * NT + tid;
      const int row = idx / GR, g = idx % GR;
      *(bf16x8*)((bf16*)outp + (am0 + row) * N + bn0 + g * 8) =
          *(const bf16x8*)(smem + row * BN + ((g ^ (row & 7)) << 3));
    }
  } else {
    // ---- f32 + residual epilogue, staged in WM passes of PR=BM/WM rows
    constexpr int PR = BM / WM;
    float* sf = (float*)smem;
#pragma unroll
    for (int h = 0; h < WM; ++h) {
      __syncthreads();
      if (wr == h) {
#pragma unroll
        for (int m = 0; m < FM; ++m) {
          const int lr0 = m * 16 + (lane >> 4) * 4;
#pragma unroll
          for (int n = 0; n < FN; ++n) {
            const int col = wc * (BN / WN) + n * 16 + (lane & 15);
            const float bv = bias[bn0 + col];
#pragma unroll
            for (int j = 0; j < 4; ++j)
              sf[(lr0 + j) * BN + col] = acc[m][n][j] + bv;
          }
        }
      }
      __syncthreads();
      constexpr int SI = PR * BN / (NT * 4);
#pragma unroll
      for (int i = 0; i < SI; ++i) {
        const int flat = (i * NT + tid) * 4;
        const int row = flat / BN, c = flat % BN;
        const size_t gi = (am0 + h * PR + row) * N + bn0 + c;
        float4 rv = *(const float4*)(res + gi);
        float4 sv = *(const float4*)(sf + row * BN + c);
        rv.x += sv.x; rv.y += sv.y; rv.z += sv.z; rv.w += sv.w;
        *(float4*)((float*)outp + gi) = rv;
      }
    }
  }
}

// ---- flash attention (causal). Q/K/V rows have stride ld; head h at +h*64
__global__ __launch_bounds__(256) void attn_k(const bf16* __restrict__ Q,
                                              const bf16* __restrict__ Kb,
                                              const bf16* __restrict__ Vb,
                                              bf16* __restrict__ Y, int ld) {
  int bh = blockIdx.x;
  int b = bh >> 4, h = bh & 15;
  int qt = blockIdx.y;
  int q0 = qt * 64;
  int tid = threadIdx.x, wid = tid >> 6, lane = tid & 63;

  __shared__ __align__(16) bf16 sK[64 * 64];
  __shared__ __align__(16) bf16 sVT[64 * 64];
  __shared__ __align__(16) bf16 sP[4][16 * 64];

  const size_t rowQ = (size_t)(b * T_ + q0 + wid * 16 + (lane & 15)) * ld + h * 64 + (lane >> 4) * 8;
  bf16x8 qf0 = *(const bf16x8*)(Q + rowQ);
  bf16x8 qf1 = *(const bf16x8*)(Q + rowQ + 32);

  float m_run[4] = {-1e30f, -1e30f, -1e30f, -1e30f};
  float l_run[4] = {0.f, 0.f, 0.f, 0.f};
  const f32x4 fz = {0.f, 0.f, 0.f, 0.f};
  f32x4 o[4];
#pragma unroll
  for (int i = 0; i < 4; ++i) o[i] = fz;

  const bf16* kg = Kb + (size_t)(b * T_ + wid * 16 + (lane >> 3)) * ld + h * 64 + (lane & 7) * 8;
  bf16* lk = sK + (wid * 16) * 64;

  for (int kt = 0; kt <= qt; ++kt) {
    int k0 = kt * 64;
#pragma unroll
    for (int i = 0; i < 2; ++i)
      gload16(kg + ((size_t)(k0 + i * 8)) * ld, lk + i * 8 * 64);
#pragma unroll
    for (int c = 0; c < 2; ++c) {
      int ch = tid + 256 * c;           // 0..511
      int r = ch >> 3, sl = ch & 7;
      bf16x8 vv = *(const bf16x8*)(Vb + (size_t)(b * T_ + k0 + r) * ld + h * 64 + sl * 8);
#pragma unroll
      for (int j = 0; j < 8; ++j)
        sVT[(sl * 8 + j) * 64 + r] = vv[j];
    }
    __syncthreads();

    f32x4 s[4];
#pragma unroll
    for (int ni = 0; ni < 4; ++ni) {
      bf16x8 kf0 = *(const bf16x8*)(sK + (ni * 16 + (lane & 15)) * 64 + (lane >> 4) * 8);
      bf16x8 kf1 = *(const bf16x8*)(sK + (ni * 16 + (lane & 15)) * 64 + 32 + (lane >> 4) * 8);
      f32x4 t = fz;
      t = MFMA16(qf0, kf0, t);
      t = MFMA16(qf1, kf1, t);
      s[ni] = t;
    }

    int rbase = q0 + wid * 16 + (lane >> 4) * 4;
    int cbase = k0 + (lane & 15);
    float tm[4] = {-1e30f, -1e30f, -1e30f, -1e30f};
#pragma unroll
    for (int ni = 0; ni < 4; ++ni)
#pragma unroll
      for (int j = 0; j < 4; ++j) {
        float v = s[ni][j] * 0.125f;
        if (cbase + ni * 16 > rbase + j) v = -1e30f;   // causal mask
        s[ni][j] = v;
        tm[j] = fmaxf(tm[j], v);
      }
#pragma unroll
    for (int j = 0; j < 4; ++j)
#pragma unroll
      for (int mk = 1; mk < 16; mk <<= 1)
        tm[j] = fmaxf(tm[j], __shfl_xor(tm[j], mk));

    float fac[4], rs[4] = {0.f, 0.f, 0.f, 0.f};
#pragma unroll
    for (int j = 0; j < 4; ++j) {
      float mn = fmaxf(m_run[j], tm[j]);
      fac[j] = __expf(m_run[j] - mn);
      m_run[j] = mn;
    }
#pragma unroll
    for (int ni = 0; ni < 4; ++ni)
#pragma unroll
      for (int j = 0; j < 4; ++j) {
        float p = __expf(s[ni][j] - m_run[j]);
        rs[j] += p;
        sP[wid][((lane >> 4) * 4 + j) * 64 + ni * 16 + (lane & 15)] = (bf16)p;
      }
#pragma unroll
    for (int j = 0; j < 4; ++j) {
#pragma unroll
      for (int mk = 1; mk < 16; mk <<= 1)
        rs[j] += __shfl_xor(rs[j], mk);
      l_run[j] = l_run[j] * fac[j] + rs[j];
    }
#pragma unroll
    for (int df = 0; df < 4; ++df)
#pragma unroll
      for (int j = 0; j < 4; ++j)
        o[df][j] *= fac[j];
    __syncthreads();

#pragma unroll
    for (int kk = 0; kk < 2; ++kk) {
      bf16x8 pf = *(const bf16x8*)(sP[wid] + (lane & 15) * 64 + kk * 32 + (lane >> 4) * 8);
#pragma unroll
      for (int df = 0; df < 4; ++df) {
        bf16x8 vf = *(const bf16x8*)(sVT + (df * 16 + (lane & 15)) * 64 + kk * 32 + (lane >> 4) * 8);
        o[df] = MFMA16(pf, vf, o[df]);
      }
    }
    __syncthreads();
  }

#pragma unroll
  for (int df = 0; df < 4; ++df)
#pragma unroll
    for (int j = 0; j < 4; ++j) {
      int row = q0 + wid * 16 + (lane >> 4) * 4 + j;
      int d = df * 16 + (lane & 15);
      Y[(size_t)(b * T_ + row) * C_ + h * 64 + d] = (bf16)(o[df][j] / l_run[j]);
    }
}

extern "C" void kernel_launch(void* const* d_in, const int* in_sizes, int n_in,
                              void* d_out, int out_size, void* d_ws, size_t ws_size,
                              hipStream_t stream) {
  (void)in_sizes; (void)n_in; (void)out_size; (void)ws_size;
  const float* x    = (const float*)d_in[0];
  const float* ln1g = (const float*)d_in[1];
  const float* ln1b = (const float*)d_in[2];
  const float* wq   = (const float*)d_in[3];
  const float* bq   = (const float*)d_in[4];
  const float* wk   = (const float*)d_in[5];
  const float* bk   = (const float*)d_in[6];
  const float* wv   = (const float*)d_in[7];
  const float* bv   = (const float*)d_in[8];
  const float* wo   = (const float*)d_in[9];
  const float* bo   = (const float*)d_in[10];
  const float* ln2g = (const float*)d_in[11];
  const float* ln2b = (const float*)d_in[12];
  const float* w1   = (const float*)d_in[13];
  const float* b1   = (const float*)d_in[14];
  const float* w2   = (const float*)d_in[15];
  const float* b2   = (const float*)d_in[16];

  char* ws = (char*)d_ws;
  const size_t MB = 1024 * 1024;
  bf16* WqkvT = (bf16*)(ws +  0 * MB);   // 6 MB  (3072 x 1024)
  bf16* WoT   = (bf16*)(ws +  6 * MB);   // 2 MB
  bf16* W1T   = (bf16*)(ws +  8 * MB);   // 8 MB
  bf16* W2T   = (bf16*)(ws + 16 * MB);   // 8 MB
  bf16* hbuf  = (bf16*)(ws + 24 * MB);   // 8 MB (ln1 out; reused for ln2 out)
  bf16* qkv   = (bf16*)(ws + 32 * MB);   // 24 MB (4096 x 3072)
  bf16* yb    = (bf16*)(ws + 56 * MB);   // 8 MB
  bf16* mb    = (bf16*)(ws + 32 * MB);   // 32 MB, reuses qkv+yb (dead by then)
  float* x1   = (float*)(ws + 64 * MB);  // 16 MB     -> total 80 MB
  float* bqkv = (float*)d_out;           // 12 KB scratch; d_out rewritten at end

  dim3 blk(256);
  wconvT<<<dim3(32, 32),  blk, 0, stream>>>(wq, WqkvT,                 1024, 1024);
  wconvT<<<dim3(32, 32),  blk, 0, stream>>>(wk, WqkvT + 1024 * 1024,   1024, 1024);
  wconvT<<<dim3(32, 32),  blk, 0, stream>>>(wv, WqkvT + 2048 * 1024,   1024, 1024);
  wconvT<<<dim3(32, 32),  blk, 0, stream>>>(wo, WoT, 1024, 1024);
  wconvT<<<dim3(128, 32), blk, 0, stream>>>(w1, W1T, 1024, 4096);
  wconvT<<<dim3(32, 128), blk, 0, stream>>>(w2, W2T, 4096, 1024);
  bcat<<<12, blk, 0, stream>>>(bq, bk, bv, bqkv);

  ln_k<<<M_, blk, 0, stream>>>(x, ln1g, ln1b, hbuf);
  gemms<128,128,2,2,0><<<768,  blk, 0, stream>>>(hbuf, WqkvT, bqkv, nullptr, qkv, 3072, 1024, 32);
  attn_k<<<dim3(64, 16), blk, 0, stream>>>(qkv, qkv + 1024, qkv + 2048, yb, 3072);
  gemms<64,128,2,2,2><<<512,   blk, 0, stream>>>(yb, WoT, bo, x, x1, 1024, 1024, 64);
  ln_k<<<M_, blk, 0, stream>>>(x1, ln2g, ln2b, hbuf);
  gemms<128,128,2,2,1><<<1024, blk, 0, stream>>>(hbuf, W1T, b1, nullptr, mb, 4096, 1024, 32);
  gemms<64,128,2,2,2><<<512,   blk, 0, stream>>>(mb, W2T, b2, x1, (float*)d_out, 1024, 4096, 64);
}

// Round 7
// 235.735 us; speedup vs baseline: 1.5208x; 1.1356x over previous
//
#include <hip/hip_runtime.h>
#include <hip/hip_bf16.h>
#include <math.h>

#define B_ 4
#define T_ 1024
#define C_ 1024
#define H_ 16
#define D_ 64
#define M_ (B_*T_)   /* 4096 rows */

typedef __bf16 bf16;
typedef __bf16 bf16x8 __attribute__((ext_vector_type(8)));
typedef float  f32x4  __attribute__((ext_vector_type(4)));

#define MFMA16(a, b, c) __builtin_amdgcn_mfma_f32_16x16x32_bf16((a), (b), (c), 0, 0, 0)

__device__ __forceinline__ void gload16(const void* g, void* l) {
  __builtin_amdgcn_global_load_lds((const __attribute__((address_space(1))) void*)g,
                                   (__attribute__((address_space(3))) void*)l,
                                   16, 0, 0);
}

// ---- weight transpose + fp32->bf16 convert: W (K x N) f32  ->  WT (N x K) bf16
__global__ __launch_bounds__(256) void wconvT(const float* __restrict__ W,
                                              bf16* __restrict__ WT, int K, int N) {
  __shared__ float tile[32][33];
  int n0 = blockIdx.x * 32, k0 = blockIdx.y * 32;
  int tx = threadIdx.x & 31, ty = threadIdx.x >> 5;  // 32 x 8
#pragma unroll
  for (int i = ty; i < 32; i += 8)
    tile[i][tx] = W[(size_t)(k0 + i) * N + n0 + tx];
  __syncthreads();
#pragma unroll
  for (int i = ty; i < 32; i += 8)
    WT[(size_t)(n0 + i) * K + k0 + tx] = (bf16)tile[tx][i];
}

// ---- concat three 1024-f32 bias vectors
__global__ __launch_bounds__(256) void bcat(const float* __restrict__ a,
                                            const float* __restrict__ b,
                                            const float* __restrict__ c,
                                            float* __restrict__ o) {
  int i = blockIdx.x * 256 + threadIdx.x;  // 0..3071
  o[i] = (i < 1024) ? a[i] : ((i < 2048) ? b[i - 1024] : c[i - 2048]);
}

// ---- LayerNorm: x (rows x 1024) f32 -> out bf16
__global__ __launch_bounds__(256) void ln_k(const float* __restrict__ x,
                                            const float* __restrict__ g,
                                            const float* __restrict__ b,
                                            bf16* __restrict__ out) {
  int row = blockIdx.x;
  int t = threadIdx.x;
  float4 xv = ((const float4*)(x + (size_t)row * C_))[t];
  float s  = xv.x + xv.y + xv.z + xv.w;
  float ss = xv.x*xv.x + xv.y*xv.y + xv.z*xv.z + xv.w*xv.w;
#pragma unroll
  for (int m = 32; m; m >>= 1) { s += __shfl_xor(s, m); ss += __shfl_xor(ss, m); }
  __shared__ float red[8];
  int wid = t >> 6;
  if ((t & 63) == 0) { red[wid] = s; red[4 + wid] = ss; }
  __syncthreads();
  s  = red[0] + red[1] + red[2] + red[3];
  ss = red[4] + red[5] + red[6] + red[7];
  float mean = s * (1.0f / C_);
  float var  = ss * (1.0f / C_) - mean * mean;
  float inv  = rsqrtf(var + 1e-5f);
  float4 gv = ((const float4*)g)[t];
  float4 bv = ((const float4*)b)[t];
  bf16* o = out + (size_t)row * C_ + t * 4;
  o[0] = (bf16)((xv.x - mean) * inv * gv.x + bv.x);
  o[1] = (bf16)((xv.y - mean) * inv * gv.y + bv.y);
  o[2] = (bf16)((xv.z - mean) * inv * gv.z + bv.z);
  o[3] = (bf16)((xv.w - mean) * inv * gv.w + bv.w);
}

// ============================================================================
// m97-structure GEMM: single-buffered LDS, 2-barrier loop, HIGH CO-RESIDENCY.
// (unchanged from R6 — see comments there)
// ============================================================================
template <int BM, int BN, int WM, int WN, int EPI>
__global__ __launch_bounds__(WM*WN*64, 4)
void gemms(const bf16* __restrict__ A, const bf16* __restrict__ BT,
           const float* __restrict__ bias, const float* __restrict__ res,
           void* __restrict__ outp, int N, int K, int gx) {
  constexpr int NT = WM * WN * 64;          // 256
  constexpr int FM = BM / WM / 16, FN = BN / WN / 16;
  constexpr int RA = BM / 32, RB = BN / 32; // staging rounds (32 rows / round)
  __shared__ __align__(16) bf16 smem[(BM + BN) * 64];
  bf16* sA = smem;
  bf16* sB = smem + BM * 64;
  const int tid = threadIdx.x, lane = tid & 63, wid = tid >> 6;
  const int wr = wid / WN, wc = wid % WN;

  int bid = blockIdx.x;
  const int nwg = gridDim.x;
  if (!(nwg & 7)) bid = (bid & 7) * (nwg >> 3) + (bid >> 3);  // T1 (bijective)
  const int bx = bid % gx, by = bid / gx;
  const size_t am0 = (size_t)bx * BM, bn0 = (size_t)by * BN;

  f32x4 acc[FM][FN];
  const f32x4 fz = {0.f, 0.f, 0.f, 0.f};
#pragma unroll
  for (int m = 0; m < FM; ++m)
#pragma unroll
    for (int n = 0; n < FN; ++n) acc[m][n] = fz;

  const int srow = tid >> 3;
  const int sg = (tid & 7) ^ (srow & 7);
  const bf16* ag = A  + (am0 + srow) * (size_t)K + sg * 8;
  const bf16* bg = BT + (bn0 + srow) * (size_t)K + sg * 8;

  const int arow = lane & 15;
  const int g0 = (((lane >> 4))     ^ (lane & 7)) * 8;  // kk=0 phys granule
  const int g1 = (((lane >> 4) + 4) ^ (lane & 7)) * 8;  // kk=1 phys granule
  const int nt = K >> 6;

  for (int t = 0; t < nt; ++t) {
#pragma unroll
    for (int r = 0; r < RA; ++r)
      gload16(ag + (size_t)t * 64 + (size_t)(r * 32) * K, sA + r * 2048 + tid * 8);
#pragma unroll
    for (int r = 0; r < RB; ++r)
      gload16(bg + (size_t)t * 64 + (size_t)(r * 32) * K, sB + r * 2048 + tid * 8);
    __syncthreads();   // drains staged loads (vmcnt 0) before compute

    const bf16* pa = sA + (wr * (BM / WM) + arow) * 64;
    const bf16* pb = sB + (wc * (BN / WN) + arow) * 64;
    bf16x8 a[FM], b[FN];
#pragma unroll
    for (int m = 0; m < FM; ++m) a[m] = *(const bf16x8*)(pa + m * 16 * 64 + g0);
#pragma unroll
    for (int n = 0; n < FN; ++n) b[n] = *(const bf16x8*)(pb + n * 16 * 64 + g0);
#pragma unroll
    for (int m = 0; m < FM; ++m)
#pragma unroll
      for (int n = 0; n < FN; ++n)
        acc[m][n] = MFMA16(a[m], b[n], acc[m][n]);
#pragma unroll
    for (int m = 0; m < FM; ++m) a[m] = *(const bf16x8*)(pa + m * 16 * 64 + g1);
#pragma unroll
    for (int n = 0; n < FN; ++n) b[n] = *(const bf16x8*)(pb + n * 16 * 64 + g1);
#pragma unroll
    for (int m = 0; m < FM; ++m)
#pragma unroll
      for (int n = 0; n < FN; ++n)
        acc[m][n] = MFMA16(a[m], b[n], acc[m][n]);
    __syncthreads();   // reads done before next stage overwrites
  }

  if constexpr (EPI != 2) {
#pragma unroll
    for (int m = 0; m < FM; ++m) {
      const int row0 = wr * (BM / WM) + m * 16 + (lane >> 4) * 4;
#pragma unroll
      for (int n = 0; n < FN; ++n) {
        const int col = wc * (BN / WN) + n * 16 + (lane & 15);
        const float bv = bias[bn0 + col];
#pragma unroll
        for (int j = 0; j < 4; ++j) {
          float v = acc[m][n][j] + bv;
          if constexpr (EPI == 1) v = 0.5f * v * (1.0f + erff(v * 0.70710678118f));
          const int rr = row0 + j;
          smem[rr * BN + (((col >> 3) ^ (rr & 7)) << 3) + (col & 7)] = (bf16)v;
        }
      }
    }
    __syncthreads();
    constexpr int GR = BN / 8;                 // granules per row
    constexpr int SI = BM * BN / (NT * 8);     // store iters
#pragma unroll
    for (int i = 0; i < SI; ++i) {
      const int idx = i * NT + tid;
      const int row = idx / GR, g = idx % GR;
      *(bf16x8*)((bf16*)outp + (am0 + row) * N + bn0 + g * 8) =
          *(const bf16x8*)(smem + row * BN + ((g ^ (row & 7)) << 3));
    }
  } else {
    constexpr int PR = BM / WM;
    float* sf = (float*)smem;
#pragma unroll
    for (int h = 0; h < WM; ++h) {
      __syncthreads();
      if (wr == h) {
#pragma unroll
        for (int m = 0; m < FM; ++m) {
          const int lr0 = m * 16 + (lane >> 4) * 4;
#pragma unroll
          for (int n = 0; n < FN; ++n) {
            const int col = wc * (BN / WN) + n * 16 + (lane & 15);
            const float bv = bias[bn0 + col];
#pragma unroll
            for (int j = 0; j < 4; ++j)
              sf[(lr0 + j) * BN + col] = acc[m][n][j] + bv;
          }
        }
      }
      __syncthreads();
      constexpr int SI = PR * BN / (NT * 4);
#pragma unroll
      for (int i = 0; i < SI; ++i) {
        const int flat = (i * NT + tid) * 4;
        const int row = flat / BN, c = flat % BN;
        const size_t gi = (am0 + h * PR + row) * N + bn0 + c;
        float4 rv = *(const float4*)(res + gi);
        float4 sv = *(const float4*)(sf + row * BN + c);
        rv.x += sv.x; rv.y += sv.y; rv.z += sv.z; rv.w += sv.w;
        *(float4*)((float*)outp + gi) = rv;
      }
    }
  }
}

// ============================================================================
// flash attention (causal), R7: granule XOR swizzle on ALL LDS tiles
// (sK / sVT / sP) -- phys granule = logical ^ (row & 7); conflict-free b128
// fragment reads since row&7 == lane&7 varies per lane.  K staged via
// global_load_lds with pre-XORed SOURCE column (rule #21).  V transposed with
// r=lane mapping (each write instr covers one full 128B row -> 2 lanes/bank).
// qt reversed so longest blocks dispatch first (tail packing).
// ============================================================================
__global__ __launch_bounds__(256) void attn_k(const bf16* __restrict__ Q,
                                              const bf16* __restrict__ Kb,
                                              const bf16* __restrict__ Vb,
                                              bf16* __restrict__ Y, int ld) {
  int bh = blockIdx.x;
  int b = bh >> 4, h = bh & 15;
  int qt = (int)gridDim.y - 1 - (int)blockIdx.y;   // longest first
  int q0 = qt * 64;
  int tid = threadIdx.x, wid = tid >> 6, lane = tid & 63;

  __shared__ __align__(16) bf16 sK[64 * 64];
  __shared__ __align__(16) bf16 sVT[64 * 64];
  __shared__ __align__(16) bf16 sP[4][16 * 64];

  const size_t rowQ = (size_t)(b * T_ + q0 + wid * 16 + (lane & 15)) * ld + h * 64 + (lane >> 4) * 8;
  bf16x8 qf0 = *(const bf16x8*)(Q + rowQ);
  bf16x8 qf1 = *(const bf16x8*)(Q + rowQ + 32);

  float m_run[4] = {-1e30f, -1e30f, -1e30f, -1e30f};
  float l_run[4] = {0.f, 0.f, 0.f, 0.f};
  const f32x4 fz = {0.f, 0.f, 0.f, 0.f};
  f32x4 o[4];
#pragma unroll
  for (int i = 0; i < 4; ++i) o[i] = fz;

  // K staging: row = wid*16 + (lane>>3) [+8 per i], source granule pre-XORed
  // with row&7 == lane>>3 (round-invariant).
  const int kgr = (lane & 7) ^ (lane >> 3);
  const bf16* kg = Kb + (size_t)(b * T_ + wid * 16 + (lane >> 3)) * ld + h * 64 + kgr * 8;
  bf16* lk = sK + (wid * 16) * 64;

  // fragment-read granules (phys = logical ^ (row&7), row&7 == lane&7)
  const int g0 = (((lane >> 4))     ^ (lane & 7)) * 8;
  const int g1 = (((lane >> 4) + 4) ^ (lane & 7)) * 8;

  for (int kt = 0; kt <= qt; ++kt) {
    int k0 = kt * 64;
#pragma unroll
    for (int i = 0; i < 2; ++i)
      gload16(kg + ((size_t)(k0 + i * 8)) * ld, lk + i * 8 * 64);
    // V transpose: thread handles k-col r=lane, d-granule sl (wid+4c).
    // write row_d = sl*8+j (row_d&7 == j), phys col granule = (r>>3)^j.
#pragma unroll
    for (int c = 0; c < 2; ++c) {
      const int r = lane, sl = wid + 4 * c;
      bf16x8 vv = *(const bf16x8*)(Vb + (size_t)(b * T_ + k0 + r) * ld + h * 64 + sl * 8);
#pragma unroll
      for (int j = 0; j < 8; ++j)
        sVT[(sl * 8 + j) * 64 + ((((r >> 3) ^ j) << 3) | (r & 7))] = vv[j];
    }
    __syncthreads();

    f32x4 s[4];
#pragma unroll
    for (int ni = 0; ni < 4; ++ni) {
      const bf16* kr = sK + (ni * 16 + (lane & 15)) * 64;
      bf16x8 kf0 = *(const bf16x8*)(kr + g0);
      bf16x8 kf1 = *(const bf16x8*)(kr + g1);
      f32x4 t = fz;
      t = MFMA16(qf0, kf0, t);
      t = MFMA16(qf1, kf1, t);
      s[ni] = t;
    }

    int rbase = q0 + wid * 16 + (lane >> 4) * 4;
    int cbase = k0 + (lane & 15);
    float tm[4] = {-1e30f, -1e30f, -1e30f, -1e30f};
#pragma unroll
    for (int ni = 0; ni < 4; ++ni)
#pragma unroll
      for (int j = 0; j < 4; ++j) {
        float v = s[ni][j] * 0.125f;
        if (cbase + ni * 16 > rbase + j) v = -1e30f;   // causal mask
        s[ni][j] = v;
        tm[j] = fmaxf(tm[j], v);
      }
#pragma unroll
    for (int j = 0; j < 4; ++j)
#pragma unroll
      for (int mk = 1; mk < 16; mk <<= 1)
        tm[j] = fmaxf(tm[j], __shfl_xor(tm[j], mk));

    float fac[4], rs[4] = {0.f, 0.f, 0.f, 0.f};
#pragma unroll
    for (int j = 0; j < 4; ++j) {
      float mn = fmaxf(m_run[j], tm[j]);
      fac[j] = __expf(m_run[j] - mn);
      m_run[j] = mn;
    }
#pragma unroll
    for (int ni = 0; ni < 4; ++ni)
#pragma unroll
      for (int j = 0; j < 4; ++j) {
        float p = __expf(s[ni][j] - m_run[j]);
        rs[j] += p;
        const int crow = (lane >> 4) * 4 + j;
        const int cg = (ni * 2 + ((lane & 15) >> 3)) ^ (crow & 7);
        sP[wid][crow * 64 + (cg << 3) + (lane & 7)] = (bf16)p;
      }
#pragma unroll
    for (int j = 0; j < 4; ++j) {
#pragma unroll
      for (int mk = 1; mk < 16; mk <<= 1)
        rs[j] += __shfl_xor(rs[j], mk);
      l_run[j] = l_run[j] * fac[j] + rs[j];
    }
#pragma unroll
    for (int df = 0; df < 4; ++df)
#pragma unroll
      for (int j = 0; j < 4; ++j)
        o[df][j] *= fac[j];
    // NOTE: no barrier needed here -- sP is wave-local; compiler inserts the
    // lgkmcnt for the ds RAW hazard.

#pragma unroll
    for (int kk = 0; kk < 2; ++kk) {
      const int gk = kk ? g1 : g0;
      bf16x8 pf = *(const bf16x8*)(sP[wid] + (lane & 15) * 64 + gk);
#pragma unroll
      for (int df = 0; df < 4; ++df) {
        bf16x8 vf = *(const bf16x8*)(sVT + (df * 16 + (lane & 15)) * 64 + gk);
        o[df] = MFMA16(pf, vf, o[df]);
      }
    }
    __syncthreads();   // protect sK/sVT from next iteration's staging
  }

#pragma unroll
  for (int df = 0; df < 4; ++df)
#pragma unroll
    for (int j = 0; j < 4; ++j) {
      int row = q0 + wid * 16 + (lane >> 4) * 4 + j;
      int d = df * 16 + (lane & 15);
      Y[(size_t)(b * T_ + row) * C_ + h * 64 + d] = (bf16)(o[df][j] / l_run[j]);
    }
}

extern "C" void kernel_launch(void* const* d_in, const int* in_sizes, int n_in,
                              void* d_out, int out_size, void* d_ws, size_t ws_size,
                              hipStream_t stream) {
  (void)in_sizes; (void)n_in; (void)out_size; (void)ws_size;
  const float* x    = (const float*)d_in[0];
  const float* ln1g = (const float*)d_in[1];
  const float* ln1b = (const float*)d_in[2];
  const float* wq   = (const float*)d_in[3];
  const float* bq   = (const float*)d_in[4];
  const float* wk   = (const float*)d_in[5];
  const float* bk   = (const float*)d_in[6];
  const float* wv   = (const float*)d_in[7];
  const float* bv   = (const float*)d_in[8];
  const float* wo   = (const float*)d_in[9];
  const float* bo   = (const float*)d_in[10];
  const float* ln2g = (const float*)d_in[11];
  const float* ln2b = (const float*)d_in[12];
  const float* w1   = (const float*)d_in[13];
  const float* b1   = (const float*)d_in[14];
  const float* w2   = (const float*)d_in[15];
  const float* b2   = (const float*)d_in[16];

  char* ws = (char*)d_ws;
  const size_t MB = 1024 * 1024;
  bf16* WqkvT = (bf16*)(ws +  0 * MB);   // 6 MB  (3072 x 1024)
  bf16* WoT   = (bf16*)(ws +  6 * MB);   // 2 MB
  bf16* W1T   = (bf16*)(ws +  8 * MB);   // 8 MB
  bf16* W2T   = (bf16*)(ws + 16 * MB);   // 8 MB
  bf16* hbuf  = (bf16*)(ws + 24 * MB);   // 8 MB (ln1 out; reused for ln2 out)
  bf16* qkv   = (bf16*)(ws + 32 * MB);   // 24 MB (4096 x 3072)
  bf16* yb    = (bf16*)(ws + 56 * MB);   // 8 MB
  bf16* mb    = (bf16*)(ws + 32 * MB);   // 32 MB, reuses qkv+yb (dead by then)
  float* x1   = (float*)(ws + 64 * MB);  // 16 MB     -> total 80 MB
  float* bqkv = (float*)d_out;           // 12 KB scratch; d_out rewritten at end

  dim3 blk(256);
  wconvT<<<dim3(32, 32),  blk, 0, stream>>>(wq, WqkvT,                 1024, 1024);
  wconvT<<<dim3(32, 32),  blk, 0, stream>>>(wk, WqkvT + 1024 * 1024,   1024, 1024);
  wconvT<<<dim3(32, 32),  blk, 0, stream>>>(wv, WqkvT + 2048 * 1024,   1024, 1024);
  wconvT<<<dim3(32, 32),  blk, 0, stream>>>(wo, WoT, 1024, 1024);
  wconvT<<<dim3(128, 32), blk, 0, stream>>>(w1, W1T, 1024, 4096);
  wconvT<<<dim3(32, 128), blk, 0, stream>>>(w2, W2T, 4096, 1024);
  bcat<<<12, blk, 0, stream>>>(bq, bk, bv, bqkv);

  ln_k<<<M_, blk, 0, stream>>>(x, ln1g, ln1b, hbuf);
  gemms<128,128,2,2,0><<<768,  blk, 0, stream>>>(hbuf, WqkvT, bqkv, nullptr, qkv, 3072, 1024, 32);
  attn_k<<<dim3(64, 16), blk, 0, stream>>>(qkv, qkv + 1024, qkv + 2048, yb, 3072);
  gemms<64,128,2,2,2><<<512,   blk, 0, stream>>>(yb, WoT, bo, x, x1, 1024, 1024, 64);
  ln_k<<<M_, blk, 0, stream>>>(x1, ln2g, ln2b, hbuf);
  gemms<128,128,2,2,1><<<1024, blk, 0, stream>>>(hbuf, W1T, b1, nullptr, mb, 4096, 1024, 32);
  gemms<64,128,2,2,2><<<512,   blk, 0, stream>>>(mb, W2T, b2, x1, (float*)d_out, 1024, 4096, 64);
}

// Round 8
// 232.726 us; speedup vs baseline: 1.5404x; 1.0129x over previous
//
#include <hip/hip_runtime.h>
#include <hip/hip_bf16.h>
#include <math.h>

#define B_ 4
#define T_ 1024
#define C_ 1024
#define H_ 16
#define D_ 64
#define M_ (B_*T_)   /* 4096 rows */

typedef __bf16 bf16;
typedef __bf16 bf16x8 __attribute__((ext_vector_type(8)));
typedef float  f32x4  __attribute__((ext_vector_type(4)));

#define MFMA16(a, b, c) __builtin_amdgcn_mfma_f32_16x16x32_bf16((a), (b), (c), 0, 0, 0)

__device__ __forceinline__ void gload16(const void* g, void* l) {
  __builtin_amdgcn_global_load_lds((const __attribute__((address_space(1))) void*)g,
                                   (__attribute__((address_space(3))) void*)l,
                                   16, 0, 0);
}

// ---- weight transpose + fp32->bf16 convert: W (K x N) f32  ->  WT (N x K) bf16
__global__ __launch_bounds__(256) void wconvT(const float* __restrict__ W,
                                              bf16* __restrict__ WT, int K, int N) {
  __shared__ float tile[32][33];
  int n0 = blockIdx.x * 32, k0 = blockIdx.y * 32;
  int tx = threadIdx.x & 31, ty = threadIdx.x >> 5;  // 32 x 8
#pragma unroll
  for (int i = ty; i < 32; i += 8)
    tile[i][tx] = W[(size_t)(k0 + i) * N + n0 + tx];
  __syncthreads();
#pragma unroll
  for (int i = ty; i < 32; i += 8)
    WT[(size_t)(n0 + i) * K + k0 + tx] = (bf16)tile[tx][i];
}

// ---- concat three 1024-f32 bias vectors
__global__ __launch_bounds__(256) void bcat(const float* __restrict__ a,
                                            const float* __restrict__ b,
                                            const float* __restrict__ c,
                                            float* __restrict__ o) {
  int i = blockIdx.x * 256 + threadIdx.x;  // 0..3071
  o[i] = (i < 1024) ? a[i] : ((i < 2048) ? b[i - 1024] : c[i - 2048]);
}

// ---- LayerNorm: x (rows x 1024) f32 -> out bf16
__global__ __launch_bounds__(256) void ln_k(const float* __restrict__ x,
                                            const float* __restrict__ g,
                                            const float* __restrict__ b,
                                            bf16* __restrict__ out) {
  int row = blockIdx.x;
  int t = threadIdx.x;
  float4 xv = ((const float4*)(x + (size_t)row * C_))[t];
  float s  = xv.x + xv.y + xv.z + xv.w;
  float ss = xv.x*xv.x + xv.y*xv.y + xv.z*xv.z + xv.w*xv.w;
#pragma unroll
  for (int m = 32; m; m >>= 1) { s += __shfl_xor(s, m); ss += __shfl_xor(ss, m); }
  __shared__ float red[8];
  int wid = t >> 6;
  if ((t & 63) == 0) { red[wid] = s; red[4 + wid] = ss; }
  __syncthreads();
  s  = red[0] + red[1] + red[2] + red[3];
  ss = red[4] + red[5] + red[6] + red[7];
  float mean = s * (1.0f / C_);
  float var  = ss * (1.0f / C_) - mean * mean;
  float inv  = rsqrtf(var + 1e-5f);
  float4 gv = ((const float4*)g)[t];
  float4 bv = ((const float4*)b)[t];
  bf16* o = out + (size_t)row * C_ + t * 4;
  o[0] = (bf16)((xv.x - mean) * inv * gv.x + bv.x);
  o[1] = (bf16)((xv.y - mean) * inv * gv.y + bv.y);
  o[2] = (bf16)((xv.z - mean) * inv * gv.z + bv.z);
  o[3] = (bf16)((xv.w - mean) * inv * gv.w + bv.w);
}

// ============================================================================
// m97-structure GEMM + T3 topology (R8): single 32KB LDS buffer, 2 barriers
// per K-tile, but stage(t+1) is issued AFTER all fragment reads complete
// (mid-sync) and BEFORE the kk1 MFMA block -- so every staged load has the
// kk1-MFMA phase plus other co-resident blocks' work to hide its latency,
// instead of being drained immediately (R6/R7 behavior: issue right before
// the drain -> full latency exposed per iteration).
// Granule XOR swizzle as in R6/R7 (conflict-free, verified 0 conflicts).
// EPI: 0 = bf16 store, 1 = gelu(erf) -> bf16, 2 = f32 store + residual add.
// T1: bijective chunked XCD swizzle on a 1-D grid (requires nwg % 8 == 0).
// ============================================================================
template <int BM, int BN, int WM, int WN, int EPI>
__global__ __launch_bounds__(WM*WN*64, 4)
void gemms(const bf16* __restrict__ A, const bf16* __restrict__ BT,
           const float* __restrict__ bias, const float* __restrict__ res,
           void* __restrict__ outp, int N, int K, int gx) {
  constexpr int NT = WM * WN * 64;          // 256
  constexpr int FM = BM / WM / 16, FN = BN / WN / 16;
  constexpr int RA = BM / 32, RB = BN / 32; // staging rounds (32 rows / round)
  __shared__ __align__(16) bf16 smem[(BM + BN) * 64];
  bf16* sA = smem;
  bf16* sB = smem + BM * 64;
  const int tid = threadIdx.x, lane = tid & 63, wid = tid >> 6;
  const int wr = wid / WN, wc = wid % WN;

  int bid = blockIdx.x;
  const int nwg = gridDim.x;
  if (!(nwg & 7)) bid = (bid & 7) * (nwg >> 3) + (bid >> 3);  // T1 (bijective)
  const int bx = bid % gx, by = bid / gx;
  const size_t am0 = (size_t)bx * BM, bn0 = (size_t)by * BN;

  f32x4 acc[FM][FN];
  const f32x4 fz = {0.f, 0.f, 0.f, 0.f};
#pragma unroll
  for (int m = 0; m < FM; ++m)
#pragma unroll
    for (int n = 0; n < FN; ++n) acc[m][n] = fz;

  const int srow = tid >> 3;
  const int sg = (tid & 7) ^ (srow & 7);
  const bf16* ag = A  + (am0 + srow) * (size_t)K + sg * 8;
  const bf16* bg = BT + (bn0 + srow) * (size_t)K + sg * 8;

  const int arow = lane & 15;
  const int g0 = (((lane >> 4))     ^ (lane & 7)) * 8;  // kk=0 phys granule
  const int g1 = (((lane >> 4) + 4) ^ (lane & 7)) * 8;  // kk=1 phys granule
  const int nt = K >> 6;

  // prologue: stage tile 0
#pragma unroll
  for (int r = 0; r < RA; ++r)
    gload16(ag + (size_t)(r * 32) * K, sA + r * 2048 + tid * 8);
#pragma unroll
  for (int r = 0; r < RB; ++r)
    gload16(bg + (size_t)(r * 32) * K, sB + r * 2048 + tid * 8);

  for (int t = 0; t < nt; ++t) {
    __syncthreads();   // drains vmcnt(0): tile t resident in LDS

    const bf16* pa = sA + (wr * (BM / WM) + arow) * 64;
    const bf16* pb = sB + (wc * (BN / WN) + arow) * 64;
    bf16x8 a[FM], b[FN];
#pragma unroll
    for (int m = 0; m < FM; ++m) a[m] = *(const bf16x8*)(pa + m * 16 * 64 + g0);
#pragma unroll
    for (int n = 0; n < FN; ++n) b[n] = *(const bf16x8*)(pb + n * 16 * 64 + g0);
#pragma unroll
    for (int m = 0; m < FM; ++m)
#pragma unroll
      for (int n = 0; n < FN; ++n)
        acc[m][n] = MFMA16(a[m], b[n], acc[m][n]);
    bf16x8 a1[FM], b1[FN];
#pragma unroll
    for (int m = 0; m < FM; ++m) a1[m] = *(const bf16x8*)(pa + m * 16 * 64 + g1);
#pragma unroll
    for (int n = 0; n < FN; ++n) b1[n] = *(const bf16x8*)(pb + n * 16 * 64 + g1);

    __syncthreads();   // all waves' ds_reads complete (no vmem outstanding)

    if (t + 1 < nt) {  // issue next tile NOW; kk1 MFMA + other blocks hide it
#pragma unroll
      for (int r = 0; r < RA; ++r)
        gload16(ag + (size_t)(t + 1) * 64 + (size_t)(r * 32) * K,
                sA + r * 2048 + tid * 8);
#pragma unroll
      for (int r = 0; r < RB; ++r)
        gload16(bg + (size_t)(t + 1) * 64 + (size_t)(r * 32) * K,
                sB + r * 2048 + tid * 8);
    }
#pragma unroll
    for (int m = 0; m < FM; ++m)
#pragma unroll
      for (int n = 0; n < FN; ++n)
        acc[m][n] = MFMA16(a1[m], b1[n], acc[m][n]);
  }

  if constexpr (EPI != 2) {
#pragma unroll
    for (int m = 0; m < FM; ++m) {
      const int row0 = wr * (BM / WM) + m * 16 + (lane >> 4) * 4;
#pragma unroll
      for (int n = 0; n < FN; ++n) {
        const int col = wc * (BN / WN) + n * 16 + (lane & 15);
        const float bv = bias[bn0 + col];
#pragma unroll
        for (int j = 0; j < 4; ++j) {
          float v = acc[m][n][j] + bv;
          if constexpr (EPI == 1) v = 0.5f * v * (1.0f + erff(v * 0.70710678118f));
          const int rr = row0 + j;
          smem[rr * BN + (((col >> 3) ^ (rr & 7)) << 3) + (col & 7)] = (bf16)v;
        }
      }
    }
    __syncthreads();
    constexpr int GR = BN / 8;                 // granules per row
    constexpr int SI = BM * BN / (NT * 8);     // store iters
#pragma unroll
    for (int i = 0; i < SI; ++i) {
      const int idx = i * NT + tid;
      const int row = idx / GR, g = idx % GR;
      *(bf16x8*)((bf16*)outp + (am0 + row) * N + bn0 + g * 8) =
          *(const bf16x8*)(smem + row * BN + ((g ^ (row & 7)) << 3));
    }
  } else {
    constexpr int PR = BM / WM;
    float* sf = (float*)smem;
#pragma unroll
    for (int h = 0; h < WM; ++h) {
      __syncthreads();
      if (wr == h) {
#pragma unroll
        for (int m = 0; m < FM; ++m) {
          const int lr0 = m * 16 + (lane >> 4) * 4;
#pragma unroll
          for (int n = 0; n < FN; ++n) {
            const int col = wc * (BN / WN) + n * 16 + (lane & 15);
            const float bv = bias[bn0 + col];
#pragma unroll
            for (int j = 0; j < 4; ++j)
              sf[(lr0 + j) * BN + col] = acc[m][n][j] + bv;
          }
        }
      }
      __syncthreads();
      constexpr int SI = PR * BN / (NT * 4);
#pragma unroll
      for (int i = 0; i < SI; ++i) {
        const int flat = (i * NT + tid) * 4;
        const int row = flat / BN, c = flat % BN;
        const size_t gi = (am0 + h * PR + row) * N + bn0 + c;
        float4 rv = *(const float4*)(res + gi);
        float4 sv = *(const float4*)(sf + row * BN + c);
        rv.x += sv.x; rv.y += sv.y; rv.z += sv.z; rv.w += sv.w;
        *(float4*)((float*)outp + gi) = rv;
      }
    }
  }
}

// ============================================================================
// flash attention (causal), as R7: granule XOR swizzle on all LDS tiles,
// r=lane V-transpose write mapping, reversed qt dispatch. (0-conflict, kept.)
// ============================================================================
__global__ __launch_bounds__(256) void attn_k(const bf16* __restrict__ Q,
                                              const bf16* __restrict__ Kb,
                                              const bf16* __restrict__ Vb,
                                              bf16* __restrict__ Y, int ld) {
  int bh = blockIdx.x;
  int b = bh >> 4, h = bh & 15;
  int qt = (int)gridDim.y - 1 - (int)blockIdx.y;   // longest first
  int q0 = qt * 64;
  int tid = threadIdx.x, wid = tid >> 6, lane = tid & 63;

  __shared__ __align__(16) bf16 sK[64 * 64];
  __shared__ __align__(16) bf16 sVT[64 * 64];
  __shared__ __align__(16) bf16 sP[4][16 * 64];

  const size_t rowQ = (size_t)(b * T_ + q0 + wid * 16 + (lane & 15)) * ld + h * 64 + (lane >> 4) * 8;
  bf16x8 qf0 = *(const bf16x8*)(Q + rowQ);
  bf16x8 qf1 = *(const bf16x8*)(Q + rowQ + 32);

  float m_run[4] = {-1e30f, -1e30f, -1e30f, -1e30f};
  float l_run[4] = {0.f, 0.f, 0.f, 0.f};
  const f32x4 fz = {0.f, 0.f, 0.f, 0.f};
  f32x4 o[4];
#pragma unroll
  for (int i = 0; i < 4; ++i) o[i] = fz;

  const int kgr = (lane & 7) ^ (lane >> 3);
  const bf16* kg = Kb + (size_t)(b * T_ + wid * 16 + (lane >> 3)) * ld + h * 64 + kgr * 8;
  bf16* lk = sK + (wid * 16) * 64;

  const int g0 = (((lane >> 4))     ^ (lane & 7)) * 8;
  const int g1 = (((lane >> 4) + 4) ^ (lane & 7)) * 8;

  for (int kt = 0; kt <= qt; ++kt) {
    int k0 = kt * 64;
#pragma unroll
    for (int i = 0; i < 2; ++i)
      gload16(kg + ((size_t)(k0 + i * 8)) * ld, lk + i * 8 * 64);
#pragma unroll
    for (int c = 0; c < 2; ++c) {
      const int r = lane, sl = wid + 4 * c;
      bf16x8 vv = *(const bf16x8*)(Vb + (size_t)(b * T_ + k0 + r) * ld + h * 64 + sl * 8);
#pragma unroll
      for (int j = 0; j < 8; ++j)
        sVT[(sl * 8 + j) * 64 + ((((r >> 3) ^ j) << 3) | (r & 7))] = vv[j];
    }
    __syncthreads();

    f32x4 s[4];
#pragma unroll
    for (int ni = 0; ni < 4; ++ni) {
      const bf16* kr = sK + (ni * 16 + (lane & 15)) * 64;
      bf16x8 kf0 = *(const bf16x8*)(kr + g0);
      bf16x8 kf1 = *(const bf16x8*)(kr + g1);
      f32x4 t = fz;
      t = MFMA16(qf0, kf0, t);
      t = MFMA16(qf1, kf1, t);
      s[ni] = t;
    }

    int rbase = q0 + wid * 16 + (lane >> 4) * 4;
    int cbase = k0 + (lane & 15);
    float tm[4] = {-1e30f, -1e30f, -1e30f, -1e30f};
#pragma unroll
    for (int ni = 0; ni < 4; ++ni)
#pragma unroll
      for (int j = 0; j < 4; ++j) {
        float v = s[ni][j] * 0.125f;
        if (cbase + ni * 16 > rbase + j) v = -1e30f;   // causal mask
        s[ni][j] = v;
        tm[j] = fmaxf(tm[j], v);
      }
#pragma unroll
    for (int j = 0; j < 4; ++j)
#pragma unroll
      for (int mk = 1; mk < 16; mk <<= 1)
        tm[j] = fmaxf(tm[j], __shfl_xor(tm[j], mk));

    float fac[4], rs[4] = {0.f, 0.f, 0.f, 0.f};
#pragma unroll
    for (int j = 0; j < 4; ++j) {
      float mn = fmaxf(m_run[j], tm[j]);
      fac[j] = __expf(m_run[j] - mn);
      m_run[j] = mn;
    }
#pragma unroll
    for (int ni = 0; ni < 4; ++ni)
#pragma unroll
      for (int j = 0; j < 4; ++j) {
        float p = __expf(s[ni][j] - m_run[j]);
        rs[j] += p;
        const int crow = (lane >> 4) * 4 + j;
        const int cg = (ni * 2 + ((lane & 15) >> 3)) ^ (crow & 7);
        sP[wid][crow * 64 + (cg << 3) + (lane & 7)] = (bf16)p;
      }
#pragma unroll
    for (int j = 0; j < 4; ++j) {
#pragma unroll
      for (int mk = 1; mk < 16; mk <<= 1)
        rs[j] += __shfl_xor(rs[j], mk);
      l_run[j] = l_run[j] * fac[j] + rs[j];
    }
#pragma unroll
    for (int df = 0; df < 4; ++df)
#pragma unroll
      for (int j = 0; j < 4; ++j)
        o[df][j] *= fac[j];

#pragma unroll
    for (int kk = 0; kk < 2; ++kk) {
      const int gk = kk ? g1 : g0;
      bf16x8 pf = *(const bf16x8*)(sP[wid] + (lane & 15) * 64 + gk);
#pragma unroll
      for (int df = 0; df < 4; ++df) {
        bf16x8 vf = *(const bf16x8*)(sVT + (df * 16 + (lane & 15)) * 64 + gk);
        o[df] = MFMA16(pf, vf, o[df]);
      }
    }
    __syncthreads();   // protect sK/sVT from next iteration's staging
  }

#pragma unroll
  for (int df = 0; df < 4; ++df)
#pragma unroll
    for (int j = 0; j < 4; ++j) {
      int row = q0 + wid * 16 + (lane >> 4) * 4 + j;
      int d = df * 16 + (lane & 15);
      Y[(size_t)(b * T_ + row) * C_ + h * 64 + d] = (bf16)(o[df][j] / l_run[j]);
    }
}

extern "C" void kernel_launch(void* const* d_in, const int* in_sizes, int n_in,
                              void* d_out, int out_size, void* d_ws, size_t ws_size,
                              hipStream_t stream) {
  (void)in_sizes; (void)n_in; (void)out_size; (void)ws_size;
  const float* x    = (const float*)d_in[0];
  const float* ln1g = (const float*)d_in[1];
  const float* ln1b = (const float*)d_in[2];
  const float* wq   = (const float*)d_in[3];
  const float* bq   = (const float*)d_in[4];
  const float* wk   = (const float*)d_in[5];
  const float* bk   = (const float*)d_in[6];
  const float* wv   = (const float*)d_in[7];
  const float* bv   = (const float*)d_in[8];
  const float* wo   = (const float*)d_in[9];
  const float* bo   = (const float*)d_in[10];
  const float* ln2g = (const float*)d_in[11];
  const float* ln2b = (const float*)d_in[12];
  const float* w1   = (const float*)d_in[13];
  const float* b1   = (const float*)d_in[14];
  const float* w2   = (const float*)d_in[15];
  const float* b2   = (const float*)d_in[16];

  char* ws = (char*)d_ws;
  const size_t MB = 1024 * 1024;
  bf16* WqkvT = (bf16*)(ws +  0 * MB);   // 6 MB  (3072 x 1024)
  bf16* WoT   = (bf16*)(ws +  6 * MB);   // 2 MB
  bf16* W1T   = (bf16*)(ws +  8 * MB);   // 8 MB
  bf16* W2T   = (bf16*)(ws + 16 * MB);   // 8 MB
  bf16* hbuf  = (bf16*)(ws + 24 * MB);   // 8 MB (ln1 out; reused for ln2 out)
  bf16* qkv   = (bf16*)(ws + 32 * MB);   // 24 MB (4096 x 3072)
  bf16* yb    = (bf16*)(ws + 56 * MB);   // 8 MB
  bf16* mb    = (bf16*)(ws + 32 * MB);   // 32 MB, reuses qkv+yb (dead by then)
  float* x1   = (float*)(ws + 64 * MB);  // 16 MB     -> total 80 MB
  float* bqkv = (float*)d_out;           // 12 KB scratch; d_out rewritten at end

  dim3 blk(256);
  wconvT<<<dim3(32, 32),  blk, 0, stream>>>(wq, WqkvT,                 1024, 1024);
  wconvT<<<dim3(32, 32),  blk, 0, stream>>>(wk, WqkvT + 1024 * 1024,   1024, 1024);
  wconvT<<<dim3(32, 32),  blk, 0, stream>>>(wv, WqkvT + 2048 * 1024,   1024, 1024);
  wconvT<<<dim3(32, 32),  blk, 0, stream>>>(wo, WoT, 1024, 1024);
  wconvT<<<dim3(128, 32), blk, 0, stream>>>(w1, W1T, 1024, 4096);
  wconvT<<<dim3(32, 128), blk, 0, stream>>>(w2, W2T, 4096, 1024);
  bcat<<<12, blk, 0, stream>>>(bq, bk, bv, bqkv);

  ln_k<<<M_, blk, 0, stream>>>(x, ln1g, ln1b, hbuf);
  gemms<128,128,2,2,0><<<768,  blk, 0, stream>>>(hbuf, WqkvT, bqkv, nullptr, qkv, 3072, 1024, 32);
  attn_k<<<dim3(64, 16), blk, 0, stream>>>(qkv, qkv + 1024, qkv + 2048, yb, 3072);
  gemms<64,128,2,2,2><<<512,   blk, 0, stream>>>(yb, WoT, bo, x, x1, 1024, 1024, 64);
  ln_k<<<M_, blk, 0, stream>>>(x1, ln2g, ln2b, hbuf);
  gemms<128,128,2,2,1><<<1024, blk, 0, stream>>>(hbuf, W1T, b1, nullptr, mb, 4096, 1024, 32);
  gemms<64,128,2,2,2><<<512,   blk, 0, stream>>>(mb, W2T, b2, x1, (float*)d_out, 1024, 4096, 64);
}

// Round 9
// 218.201 us; speedup vs baseline: 1.6430x; 1.0666x over previous
//
#include <hip/hip_runtime.h>
#include <hip/hip_bf16.h>
#include <math.h>

#define B_ 4
#define T_ 1024
#define C_ 1024
#define H_ 16
#define D_ 64
#define M_ (B_*T_)   /* 4096 rows */

typedef __bf16 bf16;
typedef __bf16 bf16x8 __attribute__((ext_vector_type(8)));
typedef float  f32x4  __attribute__((ext_vector_type(4)));

#define MFMA16(a, b, c) __builtin_amdgcn_mfma_f32_16x16x32_bf16((a), (b), (c), 0, 0, 0)

__device__ __forceinline__ void gload16(const void* g, void* l) {
  __builtin_amdgcn_global_load_lds((const __attribute__((address_space(1))) void*)g,
                                   (__attribute__((address_space(3))) void*)l,
                                   16, 0, 0);
}

// ---- unified weight prep: 6 transposes (f32 -> bf16, K x N -> N x K) in ONE
// launch.  blocks 0..3071: wq/wk/wv -> WqkvT; 3072..4095: wo -> WoT;
// 4096..8191: w1 -> W1T; 8192..12287: w2 -> W2T.
__global__ __launch_bounds__(256) void wprep(const float* __restrict__ wq,
                                             const float* __restrict__ wk,
                                             const float* __restrict__ wv,
                                             const float* __restrict__ wo,
                                             const float* __restrict__ w1,
                                             const float* __restrict__ w2,
                                             bf16* __restrict__ WqkvT,
                                             bf16* __restrict__ WoT,
                                             bf16* __restrict__ W1T,
                                             bf16* __restrict__ W2T) {
  __shared__ float tile[32][33];
  const int b = blockIdx.x;
  const float* W; bf16* WT; int K, N, n0, k0;
  if (b < 3072)      { const int w = b >> 10, t = b & 1023;
                       W = (w == 0) ? wq : ((w == 1) ? wk : wv);
                       WT = WqkvT + (size_t)w * 1024 * 1024;
                       K = 1024; N = 1024; n0 = (t & 31) * 32; k0 = (t >> 5) * 32; }
  else if (b < 4096) { const int t = b - 3072; W = wo; WT = WoT;
                       K = 1024; N = 1024; n0 = (t & 31) * 32; k0 = (t >> 5) * 32; }
  else if (b < 8192) { const int t = b - 4096; W = w1; WT = W1T;
                       K = 1024; N = 4096; n0 = (t & 127) * 32; k0 = (t >> 7) * 32; }
  else               { const int t = b - 8192; W = w2; WT = W2T;
                       K = 4096; N = 1024; n0 = (t & 31) * 32; k0 = (t >> 5) * 32; }
  const int tx = threadIdx.x & 31, ty = threadIdx.x >> 5;  // 32 x 8
#pragma unroll
  for (int i = ty; i < 32; i += 8)
    tile[i][tx] = W[(size_t)(k0 + i) * N + n0 + tx];
  __syncthreads();
#pragma unroll
  for (int i = ty; i < 32; i += 8)
    WT[(size_t)(n0 + i) * K + k0 + tx] = (bf16)tile[tx][i];
}

// ---- concat three 1024-f32 bias vectors
__global__ __launch_bounds__(256) void bcat(const float* __restrict__ a,
                                            const float* __restrict__ b,
                                            const float* __restrict__ c,
                                            float* __restrict__ o) {
  int i = blockIdx.x * 256 + threadIdx.x;  // 0..3071
  o[i] = (i < 1024) ? a[i] : ((i < 2048) ? b[i - 1024] : c[i - 2048]);
}

// ---- LayerNorm: x (rows x 1024) f32 -> out bf16
__global__ __launch_bounds__(256) void ln_k(const float* __restrict__ x,
                                            const float* __restrict__ g,
                                            const float* __restrict__ b,
                                            bf16* __restrict__ out) {
  int row = blockIdx.x;
  int t = threadIdx.x;
  float4 xv = ((const float4*)(x + (size_t)row * C_))[t];
  float s  = xv.x + xv.y + xv.z + xv.w;
  float ss = xv.x*xv.x + xv.y*xv.y + xv.z*xv.z + xv.w*xv.w;
#pragma unroll
  for (int m = 32; m; m >>= 1) { s += __shfl_xor(s, m); ss += __shfl_xor(ss, m); }
  __shared__ float red[8];
  int wid = t >> 6;
  if ((t & 63) == 0) { red[wid] = s; red[4 + wid] = ss; }
  __syncthreads();
  s  = red[0] + red[1] + red[2] + red[3];
  ss = red[4] + red[5] + red[6] + red[7];
  float mean = s * (1.0f / C_);
  float var  = ss * (1.0f / C_) - mean * mean;
  float inv  = rsqrtf(var + 1e-5f);
  float4 gv = ((const float4*)g)[t];
  float4 bv = ((const float4*)b)[t];
  bf16* o = out + (size_t)row * C_ + t * 4;
  o[0] = (bf16)((xv.x - mean) * inv * gv.x + bv.x);
  o[1] = (bf16)((xv.y - mean) * inv * gv.y + bv.y);
  o[2] = (bf16)((xv.z - mean) * inv * gv.z + bv.z);
  o[3] = (bf16)((xv.w - mean) * inv * gv.w + bv.w);
}

// ============================================================================
// m97-structure GEMM + stage-ahead (unchanged from R8; ~490 TF operating
// point of the 2-barrier/4-blocks-per-CU structure class).
// ============================================================================
template <int BM, int BN, int WM, int WN, int EPI>
__global__ __launch_bounds__(WM*WN*64, 4)
void gemms(const bf16* __restrict__ A, const bf16* __restrict__ BT,
           const float* __restrict__ bias, const float* __restrict__ res,
           void* __restrict__ outp, int N, int K, int gx) {
  constexpr int NT = WM * WN * 64;          // 256
  constexpr int FM = BM / WM / 16, FN = BN / WN / 16;
  constexpr int RA = BM / 32, RB = BN / 32; // staging rounds (32 rows / round)
  __shared__ __align__(16) bf16 smem[(BM + BN) * 64];
  bf16* sA = smem;
  bf16* sB = smem + BM * 64;
  const int tid = threadIdx.x, lane = tid & 63, wid = tid >> 6;
  const int wr = wid / WN, wc = wid % WN;

  int bid = blockIdx.x;
  const int nwg = gridDim.x;
  if (!(nwg & 7)) bid = (bid & 7) * (nwg >> 3) + (bid >> 3);  // T1 (bijective)
  const int bx = bid % gx, by = bid / gx;
  const size_t am0 = (size_t)bx * BM, bn0 = (size_t)by * BN;

  f32x4 acc[FM][FN];
  const f32x4 fz = {0.f, 0.f, 0.f, 0.f};
#pragma unroll
  for (int m = 0; m < FM; ++m)
#pragma unroll
    for (int n = 0; n < FN; ++n) acc[m][n] = fz;

  const int srow = tid >> 3;
  const int sg = (tid & 7) ^ (srow & 7);
  const bf16* ag = A  + (am0 + srow) * (size_t)K + sg * 8;
  const bf16* bg = BT + (bn0 + srow) * (size_t)K + sg * 8;

  const int arow = lane & 15;
  const int g0 = (((lane >> 4))     ^ (lane & 7)) * 8;  // kk=0 phys granule
  const int g1 = (((lane >> 4) + 4) ^ (lane & 7)) * 8;  // kk=1 phys granule
  const int nt = K >> 6;

  // prologue: stage tile 0
#pragma unroll
  for (int r = 0; r < RA; ++r)
    gload16(ag + (size_t)(r * 32) * K, sA + r * 2048 + tid * 8);
#pragma unroll
  for (int r = 0; r < RB; ++r)
    gload16(bg + (size_t)(r * 32) * K, sB + r * 2048 + tid * 8);

  for (int t = 0; t < nt; ++t) {
    __syncthreads();   // drains vmcnt(0): tile t resident in LDS

    const bf16* pa = sA + (wr * (BM / WM) + arow) * 64;
    const bf16* pb = sB + (wc * (BN / WN) + arow) * 64;
    bf16x8 a[FM], b[FN];
#pragma unroll
    for (int m = 0; m < FM; ++m) a[m] = *(const bf16x8*)(pa + m * 16 * 64 + g0);
#pragma unroll
    for (int n = 0; n < FN; ++n) b[n] = *(const bf16x8*)(pb + n * 16 * 64 + g0);
#pragma unroll
    for (int m = 0; m < FM; ++m)
#pragma unroll
      for (int n = 0; n < FN; ++n)
        acc[m][n] = MFMA16(a[m], b[n], acc[m][n]);
    bf16x8 a1[FM], b1[FN];
#pragma unroll
    for (int m = 0; m < FM; ++m) a1[m] = *(const bf16x8*)(pa + m * 16 * 64 + g1);
#pragma unroll
    for (int n = 0; n < FN; ++n) b1[n] = *(const bf16x8*)(pb + n * 16 * 64 + g1);

    __syncthreads();   // all waves' ds_reads complete (no vmem outstanding)

    if (t + 1 < nt) {  // issue next tile NOW; kk1 MFMA + other blocks hide it
#pragma unroll
      for (int r = 0; r < RA; ++r)
        gload16(ag + (size_t)(t + 1) * 64 + (size_t)(r * 32) * K,
                sA + r * 2048 + tid * 8);
#pragma unroll
      for (int r = 0; r < RB; ++r)
        gload16(bg + (size_t)(t + 1) * 64 + (size_t)(r * 32) * K,
                sB + r * 2048 + tid * 8);
    }
#pragma unroll
    for (int m = 0; m < FM; ++m)
#pragma unroll
      for (int n = 0; n < FN; ++n)
        acc[m][n] = MFMA16(a1[m], b1[n], acc[m][n]);
  }

  if constexpr (EPI != 2) {
#pragma unroll
    for (int m = 0; m < FM; ++m) {
      const int row0 = wr * (BM / WM) + m * 16 + (lane >> 4) * 4;
#pragma unroll
      for (int n = 0; n < FN; ++n) {
        const int col = wc * (BN / WN) + n * 16 + (lane & 15);
        const float bv = bias[bn0 + col];
#pragma unroll
        for (int j = 0; j < 4; ++j) {
          float v = acc[m][n][j] + bv;
          if constexpr (EPI == 1) v = 0.5f * v * (1.0f + erff(v * 0.70710678118f));
          const int rr = row0 + j;
          smem[rr * BN + (((col >> 3) ^ (rr & 7)) << 3) + (col & 7)] = (bf16)v;
        }
      }
    }
    __syncthreads();
    constexpr int GR = BN / 8;                 // granules per row
    constexpr int SI = BM * BN / (NT * 8);     // store iters
#pragma unroll
    for (int i = 0; i < SI; ++i) {
      const int idx = i * NT + tid;
      const int row = idx / GR, g = idx % GR;
      *(bf16x8*)((bf16*)outp + (am0 + row) * N + bn0 + g * 8) =
          *(const bf16x8*)(smem + row * BN + ((g ^ (row & 7)) << 3));
    }
  } else {
    constexpr int PR = BM / WM;
    float* sf = (float*)smem;
#pragma unroll
    for (int h = 0; h < WM; ++h) {
      __syncthreads();
      if (wr == h) {
#pragma unroll
        for (int m = 0; m < FM; ++m) {
          const int lr0 = m * 16 + (lane >> 4) * 4;
#pragma unroll
          for (int n = 0; n < FN; ++n) {
            const int col = wc * (BN / WN) + n * 16 + (lane & 15);
            const float bv = bias[bn0 + col];
#pragma unroll
            for (int j = 0; j < 4; ++j)
              sf[(lr0 + j) * BN + col] = acc[m][n][j] + bv;
          }
        }
      }
      __syncthreads();
      constexpr int SI = PR * BN / (NT * 4);
#pragma unroll
      for (int i = 0; i < SI; ++i) {
        const int flat = (i * NT + tid) * 4;
        const int row = flat / BN, c = flat % BN;
        const size_t gi = (am0 + h * PR + row) * N + bn0 + c;
        float4 rv = *(const float4*)(res + gi);
        float4 sv = *(const float4*)(sf + row * BN + c);
        rv.x += sv.x; rv.y += sv.y; rv.z += sv.z; rv.w += sv.w;
        *(float4*)((float*)outp + gi) = rv;
      }
    }
  }
}

// ============================================================================
// flash attention (causal), R9: double-buffered sK/sVT, ONE barrier per
// K/V-tile.  Per kt: top-sync (drains gloads issued last iter) -> issue
// K(kt+1) gload_lds + V(kt+1) reg loads -> QK / softmax / PV on cur buf
// (~1000 cy hides the loads) -> ds_write V(kt+1) into nxt buf (compiler's
// vmcnt wait lands after PV).  Granule XOR swizzle everywhere (0-conflict,
// R7-verified).  LDS 40KB -> 4 blocks/CU.
// ============================================================================
__global__ __launch_bounds__(256) void attn_k(const bf16* __restrict__ Q,
                                              const bf16* __restrict__ Kb,
                                              const bf16* __restrict__ Vb,
                                              bf16* __restrict__ Y, int ld) {
  int bh = blockIdx.x;
  int b = bh >> 4, h = bh & 15;
  int qt = (int)gridDim.y - 1 - (int)blockIdx.y;   // longest first
  int q0 = qt * 64;
  int tid = threadIdx.x, wid = tid >> 6, lane = tid & 63;

  __shared__ __align__(16) bf16 sK[2][64 * 64];
  __shared__ __align__(16) bf16 sVT[2][64 * 64];
  __shared__ __align__(16) bf16 sP[4][16 * 64];

  const size_t rowQ = (size_t)(b * T_ + q0 + wid * 16 + (lane & 15)) * ld + h * 64 + (lane >> 4) * 8;
  bf16x8 qf0 = *(const bf16x8*)(Q + rowQ);
  bf16x8 qf1 = *(const bf16x8*)(Q + rowQ + 32);

  float m_run[4] = {-1e30f, -1e30f, -1e30f, -1e30f};
  float l_run[4] = {0.f, 0.f, 0.f, 0.f};
  const f32x4 fz = {0.f, 0.f, 0.f, 0.f};
  f32x4 o[4];
#pragma unroll
  for (int i = 0; i < 4; ++i) o[i] = fz;

  // K staging: row = wid*16 + (lane>>3) [+8], source granule pre-XORed with
  // row&7 == lane>>3 (round-invariant).
  const int kgr = (lane & 7) ^ (lane >> 3);
  const bf16* kg = Kb + (size_t)(b * T_ + wid * 16 + (lane >> 3)) * ld + h * 64 + kgr * 8;
  const int lkoff = (wid * 16) * 64;
  // V loads: thread covers k-col r=lane, d-granules wid and wid+4.
  const bf16* vg = Vb + (size_t)(b * T_ + lane) * ld + h * 64;

  // fragment-read granules (phys = logical ^ (row&7), row&7 == lane&7)
  const int g0 = (((lane >> 4))     ^ (lane & 7)) * 8;
  const int g1 = (((lane >> 4) + 4) ^ (lane & 7)) * 8;

  // ---- prologue: stage kt=0 into buf 0
  gload16(kg,                   sK[0] + lkoff);
  gload16(kg + (size_t)8 * ld,  sK[0] + lkoff + 8 * 64);
  {
    bf16x8 v0 = *(const bf16x8*)(vg + wid * 8);
    bf16x8 v1 = *(const bf16x8*)(vg + (wid + 4) * 8);
#pragma unroll
    for (int j = 0; j < 8; ++j) {
      const int pc = ((((lane >> 3) ^ j) << 3) | (lane & 7));
      sVT[0][(wid * 8 + j) * 64 + pc]       = v0[j];
      sVT[0][((wid + 4) * 8 + j) * 64 + pc] = v1[j];
    }
  }

  for (int kt = 0; kt <= qt; ++kt) {
    const int cur = kt & 1, nxt = cur ^ 1;
    const bool pf = (kt < qt);
    __syncthreads();   // drains K gloads; V writes visible

    bf16x8 vn0, vn1;
    if (pf) {          // issue next tile's staging NOW
      const size_t k1 = (size_t)(kt + 1) * 64;
      gload16(kg + k1 * ld,        sK[nxt] + lkoff);
      gload16(kg + (k1 + 8) * ld,  sK[nxt] + lkoff + 8 * 64);
      vn0 = *(const bf16x8*)(vg + k1 * ld + wid * 8);
      vn1 = *(const bf16x8*)(vg + k1 * ld + (wid + 4) * 8);
    }

    const int k0 = kt * 64;
    f32x4 s[4];
#pragma unroll
    for (int ni = 0; ni < 4; ++ni) {
      const bf16* kr = sK[cur] + (ni * 16 + (lane & 15)) * 64;
      bf16x8 kf0 = *(const bf16x8*)(kr + g0);
      bf16x8 kf1 = *(const bf16x8*)(kr + g1);
      f32x4 t = fz;
      t = MFMA16(qf0, kf0, t);
      t = MFMA16(qf1, kf1, t);
      s[ni] = t;
    }

    int rbase = q0 + wid * 16 + (lane >> 4) * 4;
    int cbase = k0 + (lane & 15);
    float tm[4] = {-1e30f, -1e30f, -1e30f, -1e30f};
#pragma unroll
    for (int ni = 0; ni < 4; ++ni)
#pragma unroll
      for (int j = 0; j < 4; ++j) {
        float v = s[ni][j] * 0.125f;
        if (cbase + ni * 16 > rbase + j) v = -1e30f;   // causal mask
        s[ni][j] = v;
        tm[j] = fmaxf(tm[j], v);
      }
#pragma unroll
    for (int j = 0; j < 4; ++j)
#pragma unroll
      for (int mk = 1; mk < 16; mk <<= 1)
        tm[j] = fmaxf(tm[j], __shfl_xor(tm[j], mk));

    float fac[4], rs[4] = {0.f, 0.f, 0.f, 0.f};
#pragma unroll
    for (int j = 0; j < 4; ++j) {
      float mn = fmaxf(m_run[j], tm[j]);
      fac[j] = __expf(m_run[j] - mn);
      m_run[j] = mn;
    }
#pragma unroll
    for (int ni = 0; ni < 4; ++ni)
#pragma unroll
      for (int j = 0; j < 4; ++j) {
        float p = __expf(s[ni][j] - m_run[j]);
        rs[j] += p;
        const int crow = (lane >> 4) * 4 + j;
        const int cg = (ni * 2 + ((lane & 15) >> 3)) ^ (crow & 7);
        sP[wid][crow * 64 + (cg << 3) + (lane & 7)] = (bf16)p;
      }
#pragma unroll
    for (int j = 0; j < 4; ++j) {
#pragma unroll
      for (int mk = 1; mk < 16; mk <<= 1)
        rs[j] += __shfl_xor(rs[j], mk);
      l_run[j] = l_run[j] * fac[j] + rs[j];
    }
#pragma unroll
    for (int df = 0; df < 4; ++df)
#pragma unroll
      for (int j = 0; j < 4; ++j)
        o[df][j] *= fac[j];

#pragma unroll
    for (int kk = 0; kk < 2; ++kk) {
      const int gk = kk ? g1 : g0;
      bf16x8 pf8 = *(const bf16x8*)(sP[wid] + (lane & 15) * 64 + gk);
#pragma unroll
      for (int df = 0; df < 4; ++df) {
        bf16x8 vf = *(const bf16x8*)(sVT[cur] + (df * 16 + (lane & 15)) * 64 + gk);
        o[df] = MFMA16(pf8, vf, o[df]);
      }
    }

    if (pf) {          // write next V tile into nxt buf (vmcnt wait lands here)
#pragma unroll
      for (int j = 0; j < 8; ++j) {
        const int pc = ((((lane >> 3) ^ j) << 3) | (lane & 7));
        sVT[nxt][(wid * 8 + j) * 64 + pc]       = vn0[j];
        sVT[nxt][((wid + 4) * 8 + j) * 64 + pc] = vn1[j];
      }
    }
  }

#pragma unroll
  for (int df = 0; df < 4; ++df)
#pragma unroll
    for (int j = 0; j < 4; ++j) {
      int row = q0 + wid * 16 + (lane >> 4) * 4 + j;
      int d = df * 16 + (lane & 15);
      Y[(size_t)(b * T_ + row) * C_ + h * 64 + d] = (bf16)(o[df][j] / l_run[j]);
    }
}

extern "C" void kernel_launch(void* const* d_in, const int* in_sizes, int n_in,
                              void* d_out, int out_size, void* d_ws, size_t ws_size,
                              hipStream_t stream) {
  (void)in_sizes; (void)n_in; (void)out_size; (void)ws_size;
  const float* x    = (const float*)d_in[0];
  const float* ln1g = (const float*)d_in[1];
  const float* ln1b = (const float*)d_in[2];
  const float* wq   = (const float*)d_in[3];
  const float* bq   = (const float*)d_in[4];
  const float* wk   = (const float*)d_in[5];
  const float* bk   = (const float*)d_in[6];
  const float* wv   = (const float*)d_in[7];
  const float* bv   = (const float*)d_in[8];
  const float* wo   = (const float*)d_in[9];
  const float* bo   = (const float*)d_in[10];
  const float* ln2g = (const float*)d_in[11];
  const float* ln2b = (const float*)d_in[12];
  const float* w1   = (const float*)d_in[13];
  const float* b1   = (const float*)d_in[14];
  const float* w2   = (const float*)d_in[15];
  const float* b2   = (const float*)d_in[16];

  char* ws = (char*)d_ws;
  const size_t MB = 1024 * 1024;
  bf16* WqkvT = (bf16*)(ws +  0 * MB);   // 6 MB  (3072 x 1024)
  bf16* WoT   = (bf16*)(ws +  6 * MB);   // 2 MB
  bf16* W1T   = (bf16*)(ws +  8 * MB);   // 8 MB
  bf16* W2T   = (bf16*)(ws + 16 * MB);   // 8 MB
  bf16* hbuf  = (bf16*)(ws + 24 * MB);   // 8 MB (ln1 out; reused for ln2 out)
  bf16* qkv   = (bf16*)(ws + 32 * MB);   // 24 MB (4096 x 3072)
  bf16* yb    = (bf16*)(ws + 56 * MB);   // 8 MB
  bf16* mb    = (bf16*)(ws + 32 * MB);   // 32 MB, reuses qkv+yb (dead by then)
  float* x1   = (float*)(ws + 64 * MB);  // 16 MB     -> total 80 MB
  float* bqkv = (float*)d_out;           // 12 KB scratch; d_out rewritten at end

  dim3 blk(256);
  wprep<<<12288, blk, 0, stream>>>(wq, wk, wv, wo, w1, w2, WqkvT, WoT, W1T, W2T);
  bcat<<<12, blk, 0, stream>>>(bq, bk, bv, bqkv);

  ln_k<<<M_, blk, 0, stream>>>(x, ln1g, ln1b, hbuf);
  gemms<128,128,2,2,0><<<768,  blk, 0, stream>>>(hbuf, WqkvT, bqkv, nullptr, qkv, 3072, 1024, 32);
  attn_k<<<dim3(64, 16), blk, 0, stream>>>(qkv, qkv + 1024, qkv + 2048, yb, 3072);
  gemms<64,128,2,2,2><<<512,   blk, 0, stream>>>(yb, WoT, bo, x, x1, 1024, 1024, 64);
  ln_k<<<M_, blk, 0, stream>>>(x1, ln2g, ln2b, hbuf);
  gemms<128,128,2,2,1><<<1024, blk, 0, stream>>>(hbuf, W1T, b1, nullptr, mb, 4096, 1024, 32);
  gemms<64,128,2,2,2><<<512,   blk, 0, stream>>>(mb, W2T, b2, x1, (float*)d_out, 1024, 4096, 64);
}